// Round 1
// baseline (5101.391 us; speedup 1.0000x reference)
//
#include <hip/hip_runtime.h>
#include <cstddef>
#include <cstdint>

// Problem constants
#define L_SEQ   2048
#define BATCH_N 4
#define DMODEL  512
#define DINNER  1024
#define DSTATE  8
#define KCONV   4
#define DTRANK  32
#define NBLK    3
#define NCLS_N  10
#define MROWS   (BATCH_N * L_SEQ)   // 8192

__device__ __forceinline__ float sigmoidf_(float x) { return 1.f / (1.f + expf(-x)); }
__device__ __forceinline__ float siluf_(float x)    { return x * sigmoidf_(x); }
__device__ __forceinline__ float softplusf_(float x){ return (x > 20.f) ? x : log1pf(expf(x)); }

// ---------------------------------------------------------------------------
// Generic fp32 GEMM: C[M,N] = A[M,K] @ B[K,N] (+ epilogue)
//   epi = 0: plain store
//   epi = 1: v = softplus(v + bias[n])
//   epi = 2: v += C_old (residual, in-place)
// Requirements: M % 64 == 0, K % 16 == 0. N arbitrary (guarded).
// 64x64 block tile, 256 threads, 4x4 per-thread micro-tile, K-slice 16.
// ---------------------------------------------------------------------------
__global__ __launch_bounds__(256) void gemm_f32(
    const float* __restrict__ A, int lda,
    const float* __restrict__ B, int ldb,
    float* __restrict__ C, int ldc,
    int M, int N, int K,
    const float* __restrict__ bias, int epi)
{
    __shared__ float As[16][64];
    __shared__ float Bs[16][68];   // +4 pad

    const int tid = threadIdx.x;
    const int m0 = blockIdx.y * 64;
    const int n0 = blockIdx.x * 64;

    const int tx = tid % 16;   // n direction
    const int ty = tid / 16;   // m direction

    // A-load mapping: 64 rows x 16 k, one float4 per thread
    const int arow = tid / 4;        // 0..63
    const int akq  = (tid % 4) * 4;  // k offset 0,4,8,12
    // B-load mapping: 16 k-rows x 64 cols, one float4 per thread
    const int brow = tid / 16;       // 0..15
    const int bcol = (tid % 16) * 4; // 0..60

    const bool fullN = (n0 + 64 <= N);

    float acc[4][4];
    #pragma unroll
    for (int i = 0; i < 4; ++i)
        #pragma unroll
        for (int j = 0; j < 4; ++j) acc[i][j] = 0.f;

    for (int k0 = 0; k0 < K; k0 += 16) {
        // stage A
        {
            const float* ap = A + (size_t)(m0 + arow) * lda + (k0 + akq);
            float4 av = *(const float4*)ap;
            As[akq + 0][arow] = av.x;
            As[akq + 1][arow] = av.y;
            As[akq + 2][arow] = av.z;
            As[akq + 3][arow] = av.w;
        }
        // stage B
        {
            const int nc = n0 + bcol;
            const float* bp = B + (size_t)(k0 + brow) * ldb + nc;
            float4 bv;
            if (fullN) {
                bv = *(const float4*)bp;
            } else {
                bv.x = (nc + 0 < N) ? bp[0] : 0.f;
                bv.y = (nc + 1 < N) ? bp[1] : 0.f;
                bv.z = (nc + 2 < N) ? bp[2] : 0.f;
                bv.w = (nc + 3 < N) ? bp[3] : 0.f;
            }
            *(float4*)&Bs[brow][bcol] = bv;
        }
        __syncthreads();

        #pragma unroll
        for (int kk = 0; kk < 16; ++kk) {
            float a[4], b[4];
            #pragma unroll
            for (int i = 0; i < 4; ++i) a[i] = As[kk][ty * 4 + i];
            #pragma unroll
            for (int j = 0; j < 4; ++j) b[j] = Bs[kk][tx * 4 + j];
            #pragma unroll
            for (int i = 0; i < 4; ++i)
                #pragma unroll
                for (int j = 0; j < 4; ++j)
                    acc[i][j] = fmaf(a[i], b[j], acc[i][j]);
        }
        __syncthreads();
    }

    // epilogue
    #pragma unroll
    for (int i = 0; i < 4; ++i) {
        const int m = m0 + ty * 4 + i;
        #pragma unroll
        for (int j = 0; j < 4; ++j) {
            const int n = n0 + tx * 4 + j;
            if (n < N) {
                float v = acc[i][j];
                float* cp = C + (size_t)m * ldc + n;
                if (epi == 1)      v = softplusf_(v + bias[n]);
                else if (epi == 2) v += *cp;
                *cp = v;
            }
        }
    }
}

// ---------------------------------------------------------------------------
// Depthwise causal conv (K=4) + bias + SiLU.
// in  = xz buffer, u_pre at cols [0,1024) of rows (stride 2048)
// out = u buffer (B*L, 1024)
// ---------------------------------------------------------------------------
__global__ __launch_bounds__(256) void conv_silu_kernel(
    const float* __restrict__ xz,
    const float* __restrict__ cw,   // (1024, 4)
    const float* __restrict__ cb,   // (1024,)
    float* __restrict__ u)
{
    const int idx = blockIdx.x * 256 + threadIdx.x;   // over MROWS*DINNER
    const int d = idx & (DINNER - 1);
    const int m = idx >> 10;          // global row b*L + t
    const int t = m & (L_SEQ - 1);

    float acc = cb[d];
    #pragma unroll
    for (int k = 0; k < KCONV; ++k) {
        const int tt = t + k - (KCONV - 1);
        if (tt >= 0) {
            const size_t row = (size_t)(m - t + tt);
            acc = fmaf(xz[row * (2 * DINNER) + d], cw[d * KCONV + k], acc);
        }
    }
    u[(size_t)m * DINNER + d] = siluf_(acc);
}

// ---------------------------------------------------------------------------
// Selective scan. One thread per (b, d). h[8] in registers.
// Reads delta, u, dbl (B_t cols 32..39, C_t cols 40..47), z from xz[.,1024+d].
// Writes gated y into xz[., d] (the dead u_pre slot).
// ---------------------------------------------------------------------------
__global__ __launch_bounds__(256) void scan_kernel(
    const float* __restrict__ delta,  // (B*L, 1024)
    const float* __restrict__ u,      // (B*L, 1024)
    const float* __restrict__ dbl,    // (B*L, 48)
    float* __restrict__ xz,           // (B*L, 2048)
    const float* __restrict__ A_log,  // (1024, 8)
    const float* __restrict__ Dp)     // (1024,)
{
    const int d = (blockIdx.x & 3) * 256 + threadIdx.x;
    const int b = blockIdx.x >> 2;

    float a[DSTATE];
    #pragma unroll
    for (int n = 0; n < DSTATE; ++n) a[n] = -expf(A_log[d * DSTATE + n]);
    const float Dd = Dp[d];

    float h[DSTATE];
    #pragma unroll
    for (int n = 0; n < DSTATE; ++n) h[n] = 0.f;

    const size_t rowbase = (size_t)b * L_SEQ;
    for (int t = 0; t < L_SEQ; ++t) {
        const size_t m = rowbase + t;
        const float dt = delta[m * DINNER + d];
        const float ut = u[m * DINNER + d];
        const float du = dt * ut;
        const float* bc = dbl + m * (DTRANK + 2 * DSTATE);
        float acc = 0.f;
        #pragma unroll
        for (int n = 0; n < DSTATE; ++n) {
            h[n] = fmaf(expf(dt * a[n]), h[n], du * bc[DTRANK + n]);
            acc = fmaf(h[n], bc[DTRANK + DSTATE + n], acc);
        }
        const float z = xz[m * (2 * DINNER) + DINNER + d];
        xz[m * (2 * DINNER) + d] = fmaf(ut, Dd, acc) * siluf_(z);
    }
}

// ---------------------------------------------------------------------------
// Mean pool over L: pooled[b, dm] = mean_t x[b, t, dm]
// ---------------------------------------------------------------------------
__global__ __launch_bounds__(512) void pool_kernel(
    const float* __restrict__ x, float* __restrict__ pooled)
{
    const int b = blockIdx.x;
    const int dm = threadIdx.x;
    float s = 0.f;
    for (int t = 0; t < L_SEQ; ++t)
        s += x[((size_t)b * L_SEQ + t) * DMODEL + dm];
    pooled[b * DMODEL + dm] = s * (1.f / (float)L_SEQ);
}

// ---------------------------------------------------------------------------
// Classifier: out[b, c] = pooled[b,:] . cls_w[:, c] + cls_b[c]
// ---------------------------------------------------------------------------
__global__ __launch_bounds__(64) void cls_kernel(
    const float* __restrict__ pooled,
    const float* __restrict__ w,     // (512, 10)
    const float* __restrict__ bias,  // (10,)
    float* __restrict__ out)
{
    const int tid = threadIdx.x;
    if (tid >= BATCH_N * NCLS_N) return;
    const int b = tid / NCLS_N;
    const int c = tid % NCLS_N;
    float s = bias[c];
    for (int k = 0; k < DMODEL; ++k)
        s = fmaf(pooled[b * DMODEL + k], w[k * NCLS_N + c], s);
    out[tid] = s;
}

// ---------------------------------------------------------------------------
extern "C" void kernel_launch(void* const* d_in, const int* in_sizes, int n_in,
                              void* d_out, int out_size, void* d_ws, size_t ws_size,
                              hipStream_t stream) {
    const float* x_in      = (const float*)d_in[0];
    const float* in_proj_w = (const float*)d_in[1];   // (3, 512, 2048)
    const float* conv_w    = (const float*)d_in[2];   // (3, 1024, 4)
    const float* conv_b    = (const float*)d_in[3];   // (3, 1024)
    const float* x_proj_w  = (const float*)d_in[4];   // (3, 1024, 48)
    const float* dt_proj_w = (const float*)d_in[5];   // (3, 32, 1024)
    const float* dt_proj_b = (const float*)d_in[6];   // (3, 1024)
    const float* A_log     = (const float*)d_in[7];   // (3, 1024, 8)
    const float* Dp        = (const float*)d_in[8];   // (3, 1024)
    const float* out_proj_w= (const float*)d_in[9];   // (3, 1024, 512)
    const float* cls_w     = (const float*)d_in[10];  // (512, 10)
    const float* cls_b     = (const float*)d_in[11];  // (10,)
    float* out = (float*)d_out;

    // Workspace layout (floats)
    float* ws = (float*)d_ws;
    float* x_buf  = ws;                                  // 8192*512   = 4,194,304
    float* xz     = x_buf + (size_t)MROWS * DMODEL;      // 8192*2048  = 16,777,216
    float* u_buf  = xz    + (size_t)MROWS * 2 * DINNER;  // 8192*1024  = 8,388,608
    float* dbl    = u_buf + (size_t)MROWS * DINNER;      // 8192*48    = 393,216
    float* delta  = dbl   + (size_t)MROWS * 48;          // 8192*1024  = 8,388,608
    float* pooled = delta + (size_t)MROWS * DINNER;      // 4*512

    // x_buf <- input x
    hipMemcpyAsync(x_buf, x_in, (size_t)MROWS * DMODEL * sizeof(float),
                   hipMemcpyDeviceToDevice, stream);

    for (int blk = 0; blk < NBLK; ++blk) {
        const float* Wi  = in_proj_w + (size_t)blk * DMODEL * 2 * DINNER;
        const float* cw  = conv_w    + (size_t)blk * DINNER * KCONV;
        const float* cb  = conv_b    + (size_t)blk * DINNER;
        const float* Wx  = x_proj_w  + (size_t)blk * DINNER * (DTRANK + 2 * DSTATE);
        const float* Wdt = dt_proj_w + (size_t)blk * DTRANK * DINNER;
        const float* bdt = dt_proj_b + (size_t)blk * DINNER;
        const float* Al  = A_log     + (size_t)blk * DINNER * DSTATE;
        const float* Dv  = Dp        + (size_t)blk * DINNER;
        const float* Wo  = out_proj_w+ (size_t)blk * DINNER * DMODEL;

        // 1) xz = x @ Wi   (8192 x 2048, K=512)
        {
            dim3 grid(2 * DINNER / 64, MROWS / 64);
            gemm_f32<<<grid, 256, 0, stream>>>(x_buf, DMODEL, Wi, 2 * DINNER,
                                               xz, 2 * DINNER,
                                               MROWS, 2 * DINNER, DMODEL,
                                               nullptr, 0);
        }
        // 2) u = silu(causal_conv(u_pre) + cb)
        conv_silu_kernel<<<(MROWS * DINNER) / 256, 256, 0, stream>>>(xz, cw, cb, u_buf);
        // 3) dbl = u @ Wx  (8192 x 48, K=1024)
        {
            dim3 grid(1, MROWS / 64);
            gemm_f32<<<grid, 256, 0, stream>>>(u_buf, DINNER, Wx, DTRANK + 2 * DSTATE,
                                               dbl, DTRANK + 2 * DSTATE,
                                               MROWS, DTRANK + 2 * DSTATE, DINNER,
                                               nullptr, 0);
        }
        // 4) delta = softplus(dt @ Wdt + bdt)   (8192 x 1024, K=32)
        {
            dim3 grid(DINNER / 64, MROWS / 64);
            gemm_f32<<<grid, 256, 0, stream>>>(dbl, DTRANK + 2 * DSTATE, Wdt, DINNER,
                                               delta, DINNER,
                                               MROWS, DINNER, DTRANK,
                                               bdt, 1);
        }
        // 5) selective scan -> gated y into xz[:, 0:1024]
        scan_kernel<<<BATCH_N * (DINNER / 256), 256, 0, stream>>>(
            delta, u_buf, dbl, xz, Al, Dv);
        // 6) x += y @ Wo   (8192 x 512, K=1024)
        {
            dim3 grid(DMODEL / 64, MROWS / 64);
            gemm_f32<<<grid, 256, 0, stream>>>(xz, 2 * DINNER, Wo, DMODEL,
                                               x_buf, DMODEL,
                                               MROWS, DMODEL, DINNER,
                                               nullptr, 2);
        }
    }

    // pooled = mean over L
    pool_kernel<<<BATCH_N, DMODEL, 0, stream>>>(x_buf, pooled);
    // out = pooled @ cls_w + cls_b
    cls_kernel<<<1, 64, 0, stream>>>(pooled, cls_w, cls_b, out);
}

// Round 2
// 2055.566 us; speedup vs baseline: 2.4817x; 2.4817x over previous
//
#include <hip/hip_runtime.h>
#include <cstddef>
#include <cstdint>

// Problem constants
#define L_SEQ   2048
#define BATCH_N 4
#define DMODEL  512
#define DINNER  1024
#define DSTATE  8
#define KCONV   4
#define DTRANK  32
#define NBLK    3
#define NCLS_N  10
#define MROWS   (BATCH_N * L_SEQ)   // 8192

// Chunked-scan parameters
#define LC 64                 // chunk length
#define NC (L_SEQ / LC)       // 32 chunks

__device__ __forceinline__ float sigmoidf_(float x) { return 1.f / (1.f + expf(-x)); }
__device__ __forceinline__ float siluf_(float x)    { return x * sigmoidf_(x); }
__device__ __forceinline__ float softplusf_(float x){ return (x > 20.f) ? x : log1pf(expf(x)); }

// ---------------------------------------------------------------------------
// Generic fp32 GEMM: C[M,N] = A[M,K] @ B[K,N] (+ epilogue)
//   epi = 0: plain store
//   epi = 1: v = softplus(v + bias[n])
//   epi = 2: v += C_old (residual, in-place)
// ---------------------------------------------------------------------------
__global__ __launch_bounds__(256) void gemm_f32(
    const float* __restrict__ A, int lda,
    const float* __restrict__ B, int ldb,
    float* __restrict__ C, int ldc,
    int M, int N, int K,
    const float* __restrict__ bias, int epi)
{
    __shared__ float As[16][64];
    __shared__ float Bs[16][68];   // +4 pad

    const int tid = threadIdx.x;
    const int m0 = blockIdx.y * 64;
    const int n0 = blockIdx.x * 64;

    const int tx = tid % 16;   // n direction
    const int ty = tid / 16;   // m direction

    const int arow = tid / 4;
    const int akq  = (tid % 4) * 4;
    const int brow = tid / 16;
    const int bcol = (tid % 16) * 4;

    const bool fullN = (n0 + 64 <= N);

    float acc[4][4];
    #pragma unroll
    for (int i = 0; i < 4; ++i)
        #pragma unroll
        for (int j = 0; j < 4; ++j) acc[i][j] = 0.f;

    for (int k0 = 0; k0 < K; k0 += 16) {
        {
            const float* ap = A + (size_t)(m0 + arow) * lda + (k0 + akq);
            float4 av = *(const float4*)ap;
            As[akq + 0][arow] = av.x;
            As[akq + 1][arow] = av.y;
            As[akq + 2][arow] = av.z;
            As[akq + 3][arow] = av.w;
        }
        {
            const int nc = n0 + bcol;
            const float* bp = B + (size_t)(k0 + brow) * ldb + nc;
            float4 bv;
            if (fullN) {
                bv = *(const float4*)bp;
            } else {
                bv.x = (nc + 0 < N) ? bp[0] : 0.f;
                bv.y = (nc + 1 < N) ? bp[1] : 0.f;
                bv.z = (nc + 2 < N) ? bp[2] : 0.f;
                bv.w = (nc + 3 < N) ? bp[3] : 0.f;
            }
            *(float4*)&Bs[brow][bcol] = bv;
        }
        __syncthreads();

        #pragma unroll
        for (int kk = 0; kk < 16; ++kk) {
            float a[4], b[4];
            #pragma unroll
            for (int i = 0; i < 4; ++i) a[i] = As[kk][ty * 4 + i];
            #pragma unroll
            for (int j = 0; j < 4; ++j) b[j] = Bs[kk][tx * 4 + j];
            #pragma unroll
            for (int i = 0; i < 4; ++i)
                #pragma unroll
                for (int j = 0; j < 4; ++j)
                    acc[i][j] = fmaf(a[i], b[j], acc[i][j]);
        }
        __syncthreads();
    }

    #pragma unroll
    for (int i = 0; i < 4; ++i) {
        const int m = m0 + ty * 4 + i;
        #pragma unroll
        for (int j = 0; j < 4; ++j) {
            const int n = n0 + tx * 4 + j;
            if (n < N) {
                float v = acc[i][j];
                float* cp = C + (size_t)m * ldc + n;
                if (epi == 1)      v = softplusf_(v + bias[n]);
                else if (epi == 2) v += *cp;
                *cp = v;
            }
        }
    }
}

// ---------------------------------------------------------------------------
// Depthwise causal conv (K=4) + bias + SiLU.
// ---------------------------------------------------------------------------
__global__ __launch_bounds__(256) void conv_silu_kernel(
    const float* __restrict__ xz,
    const float* __restrict__ cw,   // (1024, 4)
    const float* __restrict__ cb,   // (1024,)
    float* __restrict__ u)
{
    const int idx = blockIdx.x * 256 + threadIdx.x;
    const int d = idx & (DINNER - 1);
    const int m = idx >> 10;
    const int t = m & (L_SEQ - 1);

    float acc = cb[d];
    #pragma unroll
    for (int k = 0; k < KCONV; ++k) {
        const int tt = t + k - (KCONV - 1);
        if (tt >= 0) {
            const size_t row = (size_t)(m - t + tt);
            acc = fmaf(xz[row * (2 * DINNER) + d], cw[d * KCONV + k], acc);
        }
    }
    u[(size_t)m * DINNER + d] = siluf_(acc);
}

// ---------------------------------------------------------------------------
// Selective scan, 3-phase chunked parallel scan.
// Phase A: per (b, chunk, d) compute chunk decay product P and local state S
//          (state assuming h_in = 0).
// Phase B: per (b, d) combine the NC chunks sequentially; overwrite P with
//          the incoming state h_in of each chunk.
// Phase C: per (b, chunk, d) re-run the chunk with h_in, produce gated y.
// Layout of P/S/Hin: [b][c][n][d] -> ((b*NC + c)*DSTATE + n)*DINNER + d
// ---------------------------------------------------------------------------
__global__ __launch_bounds__(256) void scan_chunk_kernel(
    const float* __restrict__ delta,  // (B*L, 1024)
    const float* __restrict__ u,      // (B*L, 1024)
    const float* __restrict__ dbl,    // (B*L, 48)
    const float* __restrict__ A_log,  // (1024, 8)
    float* __restrict__ Pbuf,
    float* __restrict__ Sbuf)
{
    const int c = blockIdx.x;
    const int d = blockIdx.y * 256 + threadIdx.x;
    const int b = blockIdx.z;
    const int tid = threadIdx.x;

    __shared__ float sB[LC][DSTATE];

    const size_t m0 = (size_t)b * L_SEQ + c * LC;
    // stage B_t rows: LC*8 = 512 floats, 2 per thread
    #pragma unroll
    for (int i = tid; i < LC * DSTATE; i += 256) {
        const int r = i >> 3, n = i & 7;
        sB[r][n] = dbl[(m0 + r) * (DTRANK + 2 * DSTATE) + DTRANK + n];
    }
    __syncthreads();

    float a[DSTATE], P[DSTATE], S[DSTATE];
    #pragma unroll
    for (int n = 0; n < DSTATE; ++n) {
        a[n] = -expf(A_log[d * DSTATE + n]);
        P[n] = 1.f;
        S[n] = 0.f;
    }

    for (int r = 0; r < LC; ++r) {
        const size_t m = m0 + r;
        const float dt = delta[m * DINNER + d];
        const float ut = u[m * DINNER + d];
        const float du = dt * ut;
        #pragma unroll
        for (int n = 0; n < DSTATE; ++n) {
            const float e = __expf(dt * a[n]);
            S[n] = fmaf(e, S[n], du * sB[r][n]);
            P[n] *= e;
        }
    }

    const size_t base = ((size_t)(b * NC + c) * DSTATE) * DINNER + d;
    #pragma unroll
    for (int n = 0; n < DSTATE; ++n) {
        Pbuf[base + (size_t)n * DINNER] = P[n];
        Sbuf[base + (size_t)n * DINNER] = S[n];
    }
}

__global__ __launch_bounds__(256) void scan_combine_kernel(
    float* __restrict__ Pbuf,         // in: P, out: h_in per chunk
    const float* __restrict__ Sbuf)
{
    const int g = blockIdx.x * 256 + threadIdx.x;   // over B*DINNER
    const int b = g >> 10;
    const int d = g & (DINNER - 1);

    float h[DSTATE];
    #pragma unroll
    for (int n = 0; n < DSTATE; ++n) h[n] = 0.f;

    for (int c = 0; c < NC; ++c) {
        const size_t base = ((size_t)(b * NC + c) * DSTATE) * DINNER + d;
        #pragma unroll
        for (int n = 0; n < DSTATE; ++n) {
            const size_t idx = base + (size_t)n * DINNER;
            const float p = Pbuf[idx];
            const float s = Sbuf[idx];
            Pbuf[idx] = h[n];           // store incoming state
            h[n] = fmaf(p, h[n], s);
        }
    }
}

__global__ __launch_bounds__(256) void scan_out_kernel(
    const float* __restrict__ delta,
    const float* __restrict__ u,
    const float* __restrict__ dbl,
    float* __restrict__ xz,           // z read at [.,1024+d], y written at [.,d]
    const float* __restrict__ A_log,
    const float* __restrict__ Dp,
    const float* __restrict__ Hin)    // = Pbuf after combine
{
    const int c = blockIdx.x;
    const int d = blockIdx.y * 256 + threadIdx.x;
    const int b = blockIdx.z;
    const int tid = threadIdx.x;

    __shared__ float sB[LC][DSTATE];
    __shared__ float sC[LC][DSTATE];

    const size_t m0 = (size_t)b * L_SEQ + c * LC;
    // stage B_t and C_t rows: LC*16 = 1024 floats, 4 per thread
    #pragma unroll
    for (int i = tid; i < LC * 2 * DSTATE; i += 256) {
        const int r = i >> 4, j = i & 15;
        const float v = dbl[(m0 + r) * (DTRANK + 2 * DSTATE) + DTRANK + j];
        if (j < DSTATE) sB[r][j] = v;
        else            sC[r][j - DSTATE] = v;
    }
    __syncthreads();

    float a[DSTATE], h[DSTATE];
    const size_t base = ((size_t)(b * NC + c) * DSTATE) * DINNER + d;
    #pragma unroll
    for (int n = 0; n < DSTATE; ++n) {
        a[n] = -expf(A_log[d * DSTATE + n]);
        h[n] = Hin[base + (size_t)n * DINNER];
    }
    const float Dd = Dp[d];

    for (int r = 0; r < LC; ++r) {
        const size_t m = m0 + r;
        const float dt = delta[m * DINNER + d];
        const float ut = u[m * DINNER + d];
        const float du = dt * ut;
        float acc = 0.f;
        #pragma unroll
        for (int n = 0; n < DSTATE; ++n) {
            const float e = __expf(dt * a[n]);
            h[n] = fmaf(e, h[n], du * sB[r][n]);
            acc = fmaf(h[n], sC[r][n], acc);
        }
        const float z = xz[m * (2 * DINNER) + DINNER + d];
        xz[m * (2 * DINNER) + d] = fmaf(ut, Dd, acc) * siluf_(z);
    }
}

// ---------------------------------------------------------------------------
// Mean pool, two-stage.
// ---------------------------------------------------------------------------
#define POOL_SEGS 16
__global__ __launch_bounds__(512) void pool1_kernel(
    const float* __restrict__ x, float* __restrict__ part)
{
    const int b = blockIdx.y;
    const int seg = blockIdx.x;
    const int dm = threadIdx.x;
    const int tpseg = L_SEQ / POOL_SEGS;   // 128
    float s = 0.f;
    for (int t = seg * tpseg; t < (seg + 1) * tpseg; ++t)
        s += x[((size_t)b * L_SEQ + t) * DMODEL + dm];
    part[((size_t)b * POOL_SEGS + seg) * DMODEL + dm] = s;
}

__global__ __launch_bounds__(512) void pool2_kernel(
    const float* __restrict__ part, float* __restrict__ pooled)
{
    const int b = blockIdx.x;
    const int dm = threadIdx.x;
    float s = 0.f;
    #pragma unroll
    for (int seg = 0; seg < POOL_SEGS; ++seg)
        s += part[((size_t)b * POOL_SEGS + seg) * DMODEL + dm];
    pooled[b * DMODEL + dm] = s * (1.f / (float)L_SEQ);
}

// ---------------------------------------------------------------------------
__global__ __launch_bounds__(64) void cls_kernel(
    const float* __restrict__ pooled,
    const float* __restrict__ w,     // (512, 10)
    const float* __restrict__ bias,  // (10,)
    float* __restrict__ out)
{
    const int tid = threadIdx.x;
    if (tid >= BATCH_N * NCLS_N) return;
    const int b = tid / NCLS_N;
    const int c = tid % NCLS_N;
    float s = bias[c];
    for (int k = 0; k < DMODEL; ++k)
        s = fmaf(pooled[b * DMODEL + k], w[k * NCLS_N + c], s);
    out[tid] = s;
}

// ---------------------------------------------------------------------------
extern "C" void kernel_launch(void* const* d_in, const int* in_sizes, int n_in,
                              void* d_out, int out_size, void* d_ws, size_t ws_size,
                              hipStream_t stream) {
    const float* x_in      = (const float*)d_in[0];
    const float* in_proj_w = (const float*)d_in[1];   // (3, 512, 2048)
    const float* conv_w    = (const float*)d_in[2];   // (3, 1024, 4)
    const float* conv_b    = (const float*)d_in[3];   // (3, 1024)
    const float* x_proj_w  = (const float*)d_in[4];   // (3, 1024, 48)
    const float* dt_proj_w = (const float*)d_in[5];   // (3, 32, 1024)
    const float* dt_proj_b = (const float*)d_in[6];   // (3, 1024)
    const float* A_log     = (const float*)d_in[7];   // (3, 1024, 8)
    const float* Dp        = (const float*)d_in[8];   // (3, 1024)
    const float* out_proj_w= (const float*)d_in[9];   // (3, 1024, 512)
    const float* cls_w     = (const float*)d_in[10];  // (512, 10)
    const float* cls_b     = (const float*)d_in[11];  // (10,)
    float* out = (float*)d_out;

    // Workspace layout (floats)
    float* ws = (float*)d_ws;
    float* x_buf  = ws;                                  // 4,194,304
    float* xz     = x_buf + (size_t)MROWS * DMODEL;      // 16,777,216
    float* u_buf  = xz    + (size_t)MROWS * 2 * DINNER;  // 8,388,608
    float* dbl    = u_buf + (size_t)MROWS * DINNER;      // 393,216
    float* delta  = dbl   + (size_t)MROWS * 48;          // 8,388,608
    float* pooled = delta + (size_t)MROWS * DINNER;      // 2,048
    float* Pbuf   = pooled + BATCH_N * DMODEL;           // 1,048,576
    float* Sbuf   = Pbuf + (size_t)BATCH_N * NC * DSTATE * DINNER;  // 1,048,576
    float* part   = Sbuf + (size_t)BATCH_N * NC * DSTATE * DINNER;  // 32,768

    hipMemcpyAsync(x_buf, x_in, (size_t)MROWS * DMODEL * sizeof(float),
                   hipMemcpyDeviceToDevice, stream);

    for (int blk = 0; blk < NBLK; ++blk) {
        const float* Wi  = in_proj_w + (size_t)blk * DMODEL * 2 * DINNER;
        const float* cw  = conv_w    + (size_t)blk * DINNER * KCONV;
        const float* cb  = conv_b    + (size_t)blk * DINNER;
        const float* Wx  = x_proj_w  + (size_t)blk * DINNER * (DTRANK + 2 * DSTATE);
        const float* Wdt = dt_proj_w + (size_t)blk * DTRANK * DINNER;
        const float* bdt = dt_proj_b + (size_t)blk * DINNER;
        const float* Al  = A_log     + (size_t)blk * DINNER * DSTATE;
        const float* Dv  = Dp        + (size_t)blk * DINNER;
        const float* Wo  = out_proj_w+ (size_t)blk * DINNER * DMODEL;

        // 1) xz = x @ Wi   (8192 x 2048, K=512)
        {
            dim3 grid(2 * DINNER / 64, MROWS / 64);
            gemm_f32<<<grid, 256, 0, stream>>>(x_buf, DMODEL, Wi, 2 * DINNER,
                                               xz, 2 * DINNER,
                                               MROWS, 2 * DINNER, DMODEL,
                                               nullptr, 0);
        }
        // 2) u = silu(causal_conv(u_pre) + cb)
        conv_silu_kernel<<<(MROWS * DINNER) / 256, 256, 0, stream>>>(xz, cw, cb, u_buf);
        // 3) dbl = u @ Wx  (8192 x 48, K=1024)
        {
            dim3 grid(1, MROWS / 64);
            gemm_f32<<<grid, 256, 0, stream>>>(u_buf, DINNER, Wx, DTRANK + 2 * DSTATE,
                                               dbl, DTRANK + 2 * DSTATE,
                                               MROWS, DTRANK + 2 * DSTATE, DINNER,
                                               nullptr, 0);
        }
        // 4) delta = softplus(dt @ Wdt + bdt)   (8192 x 1024, K=32)
        {
            dim3 grid(DINNER / 64, MROWS / 64);
            gemm_f32<<<grid, 256, 0, stream>>>(dbl, DTRANK + 2 * DSTATE, Wdt, DINNER,
                                               delta, DINNER,
                                               MROWS, DINNER, DTRANK,
                                               bdt, 1);
        }
        // 5) selective scan (3-phase chunked) -> gated y into xz[:, 0:1024]
        {
            dim3 gridA(NC, DINNER / 256, BATCH_N);
            scan_chunk_kernel<<<gridA, 256, 0, stream>>>(delta, u_buf, dbl, Al, Pbuf, Sbuf);
            scan_combine_kernel<<<(BATCH_N * DINNER) / 256, 256, 0, stream>>>(Pbuf, Sbuf);
            scan_out_kernel<<<gridA, 256, 0, stream>>>(delta, u_buf, dbl, xz, Al, Dv, Pbuf);
        }
        // 6) x += y @ Wo   (8192 x 512, K=1024)
        {
            dim3 grid(DMODEL / 64, MROWS / 64);
            gemm_f32<<<grid, 256, 0, stream>>>(xz, 2 * DINNER, Wo, DMODEL,
                                               x_buf, DMODEL,
                                               MROWS, DMODEL, DINNER,
                                               nullptr, 2);
        }
    }

    // pooled = mean over L (two-stage)
    {
        dim3 grid1(POOL_SEGS, BATCH_N);
        pool1_kernel<<<grid1, DMODEL, 0, stream>>>(x_buf, part);
        pool2_kernel<<<BATCH_N, DMODEL, 0, stream>>>(part, pooled);
    }
    cls_kernel<<<1, 64, 0, stream>>>(pooled, cls_w, cls_b, out);
}

// Round 3
// 883.201 us; speedup vs baseline: 5.7760x; 2.3274x over previous
//
#include <hip/hip_runtime.h>
#include <cstddef>
#include <cstdint>

// Problem constants
#define L_SEQ   2048
#define BATCH_N 4
#define DMODEL  512
#define DINNER  1024
#define DSTATE  8
#define KCONV   4
#define DTRANK  32
#define NBLK    3
#define NCLS_N  10
#define MROWS   (BATCH_N * L_SEQ)   // 8192
#define DBLW    48                  // dt_rank + 2*d_state

// Chunked-scan parameters
#define LC 64
#define NC (L_SEQ / LC)

typedef __attribute__((ext_vector_type(8))) short bf16x8;
typedef __attribute__((ext_vector_type(4))) float f32x4;

__device__ __forceinline__ float sigmoidf_(float x) { return 1.f / (1.f + expf(-x)); }
__device__ __forceinline__ float siluf_(float x)    { return x * sigmoidf_(x); }
__device__ __forceinline__ float softplusf_(float x){ return (x > 20.f) ? x : log1pf(expf(x)); }

__device__ __forceinline__ unsigned short f2bf(float f) {
    union { float f; uint32_t u; } v; v.f = f;
    const uint32_t u = v.u;
    return (unsigned short)((u + 0x7fffu + ((u >> 16) & 1u)) >> 16);  // RNE
}
__device__ __forceinline__ float bf2f(unsigned short h) {
    union { uint32_t u; float f; } v; v.u = ((uint32_t)h) << 16;
    return v.f;
}

// async global -> LDS, 16 bytes per lane; lds dest = wave-uniform base + lane*16
__device__ __forceinline__ void load_lds16(const void* g, void* l) {
    __builtin_amdgcn_global_load_lds(
        (const __attribute__((address_space(1))) unsigned int*)g,
        (__attribute__((address_space(3))) unsigned int*)l,
        16, 0, 0);
}

// ---------------------------------------------------------------------------
// bf16 MFMA GEMM: acc = A[M,K] @ Bt[N,K]^T, 128x128 tile, BK=64, 256 thr.
//   epi = 0: Obf = bf16(acc)
//   epi = 2: v = acc + Xres; Xres = v (fp32); Obf = bf16(v)
// M, N multiples of 128; K multiple of 64.
// ---------------------------------------------------------------------------
__global__ __launch_bounds__(256) void gemm_bf16(
    const unsigned short* __restrict__ A, int lda,
    const unsigned short* __restrict__ Bt, int ldb,
    int K, int ldc,
    unsigned short* __restrict__ Obf,
    float* __restrict__ Xres,
    int epi)
{
    __shared__ unsigned short sA[128 * 64];   // [row][k], row stride 64
    __shared__ unsigned short sB[128 * 64];   // [n][k]

    const int tid  = threadIdx.x;
    const int lane = tid & 63;
    const int wave = tid >> 6;
    const int m0 = blockIdx.y * 128;
    const int n0 = blockIdx.x * 128;
    const int wm = (wave >> 1) * 64;
    const int wn = (wave & 1) * 64;
    const int lm = lane & 15;
    const int lq = lane >> 4;

    const int srow = lane >> 3;         // 0..7 (row within 8-row chunk)
    const int scol = (lane & 7) * 8;    // k-elem offset (16B per lane)

    f32x4 acc[4][4];
    #pragma unroll
    for (int i = 0; i < 4; ++i)
        #pragma unroll
        for (int j = 0; j < 4; ++j) acc[i][j] = (f32x4){0.f, 0.f, 0.f, 0.f};

    for (int k0 = 0; k0 < K; k0 += 64) {
        #pragma unroll
        for (int j = 0; j < 4; ++j) {
            const int c = j * 4 + wave;   // chunk 0..15 -> rows 8c..8c+7
            load_lds16(A  + (size_t)(m0 + c * 8 + srow) * lda + k0 + scol, &sA[c * 512]);
            load_lds16(Bt + (size_t)(n0 + c * 8 + srow) * ldb + k0 + scol, &sB[c * 512]);
        }
        __syncthreads();
        #pragma unroll
        for (int ks = 0; ks < 2; ++ks) {
            bf16x8 aF[4], bF[4];
            #pragma unroll
            for (int mt = 0; mt < 4; ++mt)
                aF[mt] = *(const bf16x8*)&sA[(wm + mt * 16 + lm) * 64 + ks * 32 + lq * 8];
            #pragma unroll
            for (int nt = 0; nt < 4; ++nt)
                bF[nt] = *(const bf16x8*)&sB[(wn + nt * 16 + lm) * 64 + ks * 32 + lq * 8];
            #pragma unroll
            for (int mt = 0; mt < 4; ++mt)
                #pragma unroll
                for (int nt = 0; nt < 4; ++nt)
                    acc[mt][nt] = __builtin_amdgcn_mfma_f32_16x16x32_bf16(
                        aF[mt], bF[nt], acc[mt][nt], 0, 0, 0);
        }
        __syncthreads();
    }

    // epilogue: C/D layout col=lane&15, row=(lane>>4)*4+reg
    #pragma unroll
    for (int mt = 0; mt < 4; ++mt) {
        #pragma unroll
        for (int nt = 0; nt < 4; ++nt) {
            #pragma unroll
            for (int r = 0; r < 4; ++r) {
                const int row = m0 + wm + mt * 16 + lq * 4 + r;
                const int col = n0 + wn + nt * 16 + lm;
                const size_t idx = (size_t)row * ldc + col;
                float v = acc[mt][nt][r];
                if (epi == 2) {
                    v += Xres[idx];
                    Xres[idx] = v;
                }
                Obf[idx] = f2bf(v);
            }
        }
    }
}

// ---------------------------------------------------------------------------
// x_proj: dbl[M,48] += u_bf[M,1024] @ Wxt[48,1024]^T, split-K=4, no LDS
// (A has zero reuse across blocks; B is 96 KB, L2-hot). atomicAdd fp32.
// ---------------------------------------------------------------------------
__global__ __launch_bounds__(256) void gemm_xproj(
    const unsigned short* __restrict__ ub,
    const unsigned short* __restrict__ Wxt,
    float* __restrict__ dbl)
{
    const int tid = threadIdx.x, lane = tid & 63, wave = tid >> 6;
    const int lm = lane & 15, lq = lane >> 4;
    const int rowA = blockIdx.x * 128 + wave * 32;
    const int k0 = blockIdx.y * 256;

    f32x4 acc[2][3];
    #pragma unroll
    for (int i = 0; i < 2; ++i)
        #pragma unroll
        for (int j = 0; j < 3; ++j) acc[i][j] = (f32x4){0.f, 0.f, 0.f, 0.f};

    for (int kk = 0; kk < 256; kk += 32) {
        const int k = k0 + kk;
        bf16x8 aF[2], bF[3];
        #pragma unroll
        for (int mt = 0; mt < 2; ++mt)
            aF[mt] = *(const bf16x8*)&ub[(size_t)(rowA + mt * 16 + lm) * DINNER + k + lq * 8];
        #pragma unroll
        for (int nt = 0; nt < 3; ++nt)
            bF[nt] = *(const bf16x8*)&Wxt[(size_t)(nt * 16 + lm) * DINNER + k + lq * 8];
        #pragma unroll
        for (int mt = 0; mt < 2; ++mt)
            #pragma unroll
            for (int nt = 0; nt < 3; ++nt)
                acc[mt][nt] = __builtin_amdgcn_mfma_f32_16x16x32_bf16(
                    aF[mt], bF[nt], acc[mt][nt], 0, 0, 0);
    }
    #pragma unroll
    for (int mt = 0; mt < 2; ++mt)
        #pragma unroll
        for (int nt = 0; nt < 3; ++nt)
            #pragma unroll
            for (int r = 0; r < 4; ++r)
                atomicAdd(&dbl[(size_t)(rowA + mt * 16 + lq * 4 + r) * DBLW + nt * 16 + lm],
                          acc[mt][nt][r]);
}

__global__ void zero_f32(float* __restrict__ p, int n4) {
    const int i = blockIdx.x * 256 + threadIdx.x;
    if (i < n4) ((f32x4*)p)[i] = (f32x4){0.f, 0.f, 0.f, 0.f};
}

// ---------------------------------------------------------------------------
// Weight transpose + cast: out[n][k] bf16 = in[k][n] fp32
// ---------------------------------------------------------------------------
__global__ __launch_bounds__(256) void transpose_cast(
    const float* __restrict__ in, unsigned short* __restrict__ out,
    int Kdim, int Ndim, size_t in_stride, size_t out_stride)
{
    __shared__ float s[32][33];
    const float* ip = in + blockIdx.z * in_stride;
    unsigned short* op = out + blockIdx.z * out_stride;
    const int bx = blockIdx.x * 32;   // over Ndim
    const int by = blockIdx.y * 32;   // over Kdim
    const int t = threadIdx.x;
    const int r = t >> 3;
    const int c4 = (t & 7) * 4;

    const int row = by + r;
    if (bx + c4 + 3 < Ndim) {
        float4 v = *(const float4*)&ip[(size_t)row * Ndim + bx + c4];
        s[r][c4 + 0] = v.x; s[r][c4 + 1] = v.y; s[r][c4 + 2] = v.z; s[r][c4 + 3] = v.w;
    } else {
        for (int i = 0; i < 4; ++i) {
            const int col = bx + c4 + i;
            s[r][c4 + i] = (col < Ndim) ? ip[(size_t)row * Ndim + col] : 0.f;
        }
    }
    __syncthreads();
    if (bx + r < Ndim) {
        unsigned short w0 = f2bf(s[c4 + 0][r]), w1 = f2bf(s[c4 + 1][r]);
        unsigned short w2 = f2bf(s[c4 + 2][r]), w3 = f2bf(s[c4 + 3][r]);
        uint2 pk;
        pk.x = (uint32_t)w0 | ((uint32_t)w1 << 16);
        pk.y = (uint32_t)w2 | ((uint32_t)w3 << 16);
        *(uint2*)&op[(size_t)(bx + r) * Kdim + by + c4] = pk;
    }
}

__global__ void cast_bf16(const float* __restrict__ in, unsigned short* __restrict__ out, int n4) {
    const int i = blockIdx.x * 256 + threadIdx.x;
    if (i >= n4) return;
    float4 v = ((const float4*)in)[i];
    uint2 pk;
    pk.x = (uint32_t)f2bf(v.x) | ((uint32_t)f2bf(v.y) << 16);
    pk.y = (uint32_t)f2bf(v.z) | ((uint32_t)f2bf(v.w) << 16);
    ((uint2*)out)[i] = pk;
}

// ---------------------------------------------------------------------------
// fp32 SIMT GEMM (kept for dt_proj: K=32): C = A@B, epi=1: softplus(v+bias[n])
// ---------------------------------------------------------------------------
__global__ __launch_bounds__(256) void gemm_f32(
    const float* __restrict__ A, int lda,
    const float* __restrict__ B, int ldb,
    float* __restrict__ C, int ldc,
    int M, int N, int K,
    const float* __restrict__ bias, int epi)
{
    __shared__ float As[16][64];
    __shared__ float Bs[16][68];

    const int tid = threadIdx.x;
    const int m0 = blockIdx.y * 64;
    const int n0 = blockIdx.x * 64;
    const int tx = tid % 16;
    const int ty = tid / 16;
    const int arow = tid / 4;
    const int akq  = (tid % 4) * 4;
    const int brow = tid / 16;
    const int bcol = (tid % 16) * 4;
    const bool fullN = (n0 + 64 <= N);

    float acc[4][4];
    #pragma unroll
    for (int i = 0; i < 4; ++i)
        #pragma unroll
        for (int j = 0; j < 4; ++j) acc[i][j] = 0.f;

    for (int k0 = 0; k0 < K; k0 += 16) {
        {
            const float* ap = A + (size_t)(m0 + arow) * lda + (k0 + akq);
            float4 av = *(const float4*)ap;
            As[akq + 0][arow] = av.x;
            As[akq + 1][arow] = av.y;
            As[akq + 2][arow] = av.z;
            As[akq + 3][arow] = av.w;
        }
        {
            const int nc = n0 + bcol;
            const float* bp = B + (size_t)(k0 + brow) * ldb + nc;
            float4 bv;
            if (fullN) {
                bv = *(const float4*)bp;
            } else {
                bv.x = (nc + 0 < N) ? bp[0] : 0.f;
                bv.y = (nc + 1 < N) ? bp[1] : 0.f;
                bv.z = (nc + 2 < N) ? bp[2] : 0.f;
                bv.w = (nc + 3 < N) ? bp[3] : 0.f;
            }
            *(float4*)&Bs[brow][bcol] = bv;
        }
        __syncthreads();
        #pragma unroll
        for (int kk = 0; kk < 16; ++kk) {
            float a[4], b[4];
            #pragma unroll
            for (int i = 0; i < 4; ++i) a[i] = As[kk][ty * 4 + i];
            #pragma unroll
            for (int j = 0; j < 4; ++j) b[j] = Bs[kk][tx * 4 + j];
            #pragma unroll
            for (int i = 0; i < 4; ++i)
                #pragma unroll
                for (int j = 0; j < 4; ++j)
                    acc[i][j] = fmaf(a[i], b[j], acc[i][j]);
        }
        __syncthreads();
    }

    #pragma unroll
    for (int i = 0; i < 4; ++i) {
        const int m = m0 + ty * 4 + i;
        #pragma unroll
        for (int j = 0; j < 4; ++j) {
            const int n = n0 + tx * 4 + j;
            if (n < N) {
                float v = acc[i][j];
                float* cp = C + (size_t)m * ldc + n;
                if (epi == 1)      v = softplusf_(v + bias[n]);
                else if (epi == 2) v += *cp;
                *cp = v;
            }
        }
    }
}

// ---------------------------------------------------------------------------
// Depthwise causal conv (K=4) + bias + SiLU; bf16 in (xz lo half), bf16 out.
// ---------------------------------------------------------------------------
__global__ __launch_bounds__(256) void conv_silu_kernel(
    const unsigned short* __restrict__ xz,
    const float* __restrict__ cw,
    const float* __restrict__ cb,
    unsigned short* __restrict__ ub)
{
    const int idx = blockIdx.x * 256 + threadIdx.x;
    const int d = idx & (DINNER - 1);
    const int m = idx >> 10;
    const int t = m & (L_SEQ - 1);

    float acc = cb[d];
    #pragma unroll
    for (int k = 0; k < KCONV; ++k) {
        const int tt = t + k - (KCONV - 1);
        if (tt >= 0)
            acc = fmaf(bf2f(xz[(size_t)(m - t + tt) * (2 * DINNER) + d]), cw[d * KCONV + k], acc);
    }
    ub[(size_t)m * DINNER + d] = f2bf(siluf_(acc));
}

// ---------------------------------------------------------------------------
// 3-phase chunked selective scan (verified in R1), u now bf16.
// ---------------------------------------------------------------------------
__global__ __launch_bounds__(256) void scan_chunk_kernel(
    const float* __restrict__ delta,
    const unsigned short* __restrict__ ub,
    const float* __restrict__ dbl,
    const float* __restrict__ A_log,
    float* __restrict__ Pbuf,
    float* __restrict__ Sbuf)
{
    const int c = blockIdx.x;
    const int d = blockIdx.y * 256 + threadIdx.x;
    const int b = blockIdx.z;
    const int tid = threadIdx.x;

    __shared__ float sB[LC][DSTATE];

    const size_t m0 = (size_t)b * L_SEQ + c * LC;
    #pragma unroll
    for (int i = tid; i < LC * DSTATE; i += 256) {
        const int r = i >> 3, n = i & 7;
        sB[r][n] = dbl[(m0 + r) * DBLW + DTRANK + n];
    }
    __syncthreads();

    float a[DSTATE], P[DSTATE], S[DSTATE];
    #pragma unroll
    for (int n = 0; n < DSTATE; ++n) {
        a[n] = -expf(A_log[d * DSTATE + n]);
        P[n] = 1.f;
        S[n] = 0.f;
    }

    for (int r = 0; r < LC; ++r) {
        const size_t m = m0 + r;
        const float dt = delta[m * DINNER + d];
        const float ut = bf2f(ub[m * DINNER + d]);
        const float du = dt * ut;
        #pragma unroll
        for (int n = 0; n < DSTATE; ++n) {
            const float e = __expf(dt * a[n]);
            S[n] = fmaf(e, S[n], du * sB[r][n]);
            P[n] *= e;
        }
    }

    const size_t base = ((size_t)(b * NC + c) * DSTATE) * DINNER + d;
    #pragma unroll
    for (int n = 0; n < DSTATE; ++n) {
        Pbuf[base + (size_t)n * DINNER] = P[n];
        Sbuf[base + (size_t)n * DINNER] = S[n];
    }
}

__global__ __launch_bounds__(256) void scan_combine_kernel(
    float* __restrict__ Pbuf,
    const float* __restrict__ Sbuf)
{
    const int g = blockIdx.x * 256 + threadIdx.x;
    const int b = g >> 10;
    const int d = g & (DINNER - 1);

    float h[DSTATE];
    #pragma unroll
    for (int n = 0; n < DSTATE; ++n) h[n] = 0.f;

    for (int c = 0; c < NC; ++c) {
        const size_t base = ((size_t)(b * NC + c) * DSTATE) * DINNER + d;
        #pragma unroll
        for (int n = 0; n < DSTATE; ++n) {
            const size_t idx = base + (size_t)n * DINNER;
            const float p = Pbuf[idx];
            const float s = Sbuf[idx];
            Pbuf[idx] = h[n];
            h[n] = fmaf(p, h[n], s);
        }
    }
}

__global__ __launch_bounds__(256) void scan_out_kernel(
    const float* __restrict__ delta,
    const unsigned short* __restrict__ ub,
    const float* __restrict__ dbl,
    const unsigned short* __restrict__ xz,   // z at [., 1024+d]
    const float* __restrict__ A_log,
    const float* __restrict__ Dp,
    const float* __restrict__ Hin,
    unsigned short* __restrict__ ybuf)
{
    const int c = blockIdx.x;
    const int d = blockIdx.y * 256 + threadIdx.x;
    const int b = blockIdx.z;
    const int tid = threadIdx.x;

    __shared__ float sB[LC][DSTATE];
    __shared__ float sC[LC][DSTATE];

    const size_t m0 = (size_t)b * L_SEQ + c * LC;
    #pragma unroll
    for (int i = tid; i < LC * 2 * DSTATE; i += 256) {
        const int r = i >> 4, j = i & 15;
        const float v = dbl[(m0 + r) * DBLW + DTRANK + j];
        if (j < DSTATE) sB[r][j] = v;
        else            sC[r][j - DSTATE] = v;
    }
    __syncthreads();

    float a[DSTATE], h[DSTATE];
    const size_t base = ((size_t)(b * NC + c) * DSTATE) * DINNER + d;
    #pragma unroll
    for (int n = 0; n < DSTATE; ++n) {
        a[n] = -expf(A_log[d * DSTATE + n]);
        h[n] = Hin[base + (size_t)n * DINNER];
    }
    const float Dd = Dp[d];

    for (int r = 0; r < LC; ++r) {
        const size_t m = m0 + r;
        const float dt = delta[m * DINNER + d];
        const float ut = bf2f(ub[m * DINNER + d]);
        const float du = dt * ut;
        float acc = 0.f;
        #pragma unroll
        for (int n = 0; n < DSTATE; ++n) {
            const float e = __expf(dt * a[n]);
            h[n] = fmaf(e, h[n], du * sB[r][n]);
            acc = fmaf(h[n], sC[r][n], acc);
        }
        const float z = bf2f(xz[m * (2 * DINNER) + DINNER + d]);
        ybuf[m * DINNER + d] = f2bf(fmaf(ut, Dd, acc) * siluf_(z));
    }
}

// ---------------------------------------------------------------------------
#define POOL_SEGS 16
__global__ __launch_bounds__(512) void pool1_kernel(
    const float* __restrict__ x, float* __restrict__ part)
{
    const int b = blockIdx.y;
    const int seg = blockIdx.x;
    const int dm = threadIdx.x;
    const int tpseg = L_SEQ / POOL_SEGS;
    float s = 0.f;
    for (int t = seg * tpseg; t < (seg + 1) * tpseg; ++t)
        s += x[((size_t)b * L_SEQ + t) * DMODEL + dm];
    part[((size_t)b * POOL_SEGS + seg) * DMODEL + dm] = s;
}

__global__ __launch_bounds__(512) void pool2_kernel(
    const float* __restrict__ part, float* __restrict__ pooled)
{
    const int b = blockIdx.x;
    const int dm = threadIdx.x;
    float s = 0.f;
    #pragma unroll
    for (int seg = 0; seg < POOL_SEGS; ++seg)
        s += part[((size_t)b * POOL_SEGS + seg) * DMODEL + dm];
    pooled[b * DMODEL + dm] = s * (1.f / (float)L_SEQ);
}

__global__ __launch_bounds__(64) void cls_kernel(
    const float* __restrict__ pooled,
    const float* __restrict__ w,
    const float* __restrict__ bias,
    float* __restrict__ out)
{
    const int tid = threadIdx.x;
    if (tid >= BATCH_N * NCLS_N) return;
    const int b = tid / NCLS_N;
    const int c = tid % NCLS_N;
    float s = bias[c];
    for (int k = 0; k < DMODEL; ++k)
        s = fmaf(pooled[b * DMODEL + k], w[k * NCLS_N + c], s);
    out[tid] = s;
}

// ---------------------------------------------------------------------------
extern "C" void kernel_launch(void* const* d_in, const int* in_sizes, int n_in,
                              void* d_out, int out_size, void* d_ws, size_t ws_size,
                              hipStream_t stream) {
    const float* x_in      = (const float*)d_in[0];
    const float* in_proj_w = (const float*)d_in[1];   // (3, 512, 2048)
    const float* conv_w    = (const float*)d_in[2];   // (3, 1024, 4)
    const float* conv_b    = (const float*)d_in[3];   // (3, 1024)
    const float* x_proj_w  = (const float*)d_in[4];   // (3, 1024, 48)
    const float* dt_proj_w = (const float*)d_in[5];   // (3, 32, 1024)
    const float* dt_proj_b = (const float*)d_in[6];   // (3, 1024)
    const float* A_log     = (const float*)d_in[7];   // (3, 1024, 8)
    const float* Dp        = (const float*)d_in[8];   // (3, 1024)
    const float* out_proj_w= (const float*)d_in[9];   // (3, 1024, 512)
    const float* cls_w     = (const float*)d_in[10];  // (512, 10)
    const float* cls_b     = (const float*)d_in[11];  // (10,)
    float* out = (float*)d_out;

    // Workspace layout (bytes, 256-aligned); total ~150 MB
    char* w = (char*)d_ws;
    auto alloc = [&](size_t bytes) { char* p = w; w += (bytes + 255) & ~(size_t)255; return p; };
    float*          x_buf  = (float*)         alloc((size_t)MROWS * DMODEL * 4);       // 16 MB
    unsigned short* xz_bf  = (unsigned short*)alloc((size_t)MROWS * 2 * DINNER * 2);   // 32 MB
    unsigned short* ub     = (unsigned short*)alloc((size_t)MROWS * DINNER * 2);       // 16 MB
    float*          delta  = (float*)         alloc((size_t)MROWS * DINNER * 4);       // 32 MB
    float*          dbl    = (float*)         alloc((size_t)MROWS * DBLW * 4);         // 1.5 MB
    float*          Pbuf   = (float*)         alloc((size_t)BATCH_N * NC * DSTATE * DINNER * 4);
    float*          Sbuf   = (float*)         alloc((size_t)BATCH_N * NC * DSTATE * DINNER * 4);
    unsigned short* xb     = (unsigned short*)alloc((size_t)MROWS * DMODEL * 2);       // 8 MB
    unsigned short* ybuf   = (unsigned short*)alloc((size_t)MROWS * DINNER * 2);       // 16 MB
    unsigned short* Wit    = (unsigned short*)alloc((size_t)NBLK * 2048 * 512 * 2);    // 6 MB
    unsigned short* Wot    = (unsigned short*)alloc((size_t)NBLK * 512 * 1024 * 2);    // 3 MB
    unsigned short* Wxt    = (unsigned short*)alloc((size_t)NBLK * DBLW * 1024 * 2);   // 0.3 MB
    float*          part   = (float*)         alloc((size_t)BATCH_N * POOL_SEGS * DMODEL * 4);
    float*          pooled = (float*)         alloc((size_t)BATCH_N * DMODEL * 4);

    // Prep: residual fp32, bf16 cast of x, weight transposes+casts
    hipMemcpyAsync(x_buf, x_in, (size_t)MROWS * DMODEL * sizeof(float),
                   hipMemcpyDeviceToDevice, stream);
    cast_bf16<<<(MROWS * DMODEL / 4) / 256, 256, 0, stream>>>(x_in, xb, MROWS * DMODEL / 4);
    transpose_cast<<<dim3(2048 / 32, 512 / 32, NBLK), 256, 0, stream>>>(
        in_proj_w, Wit, 512, 2048, (size_t)512 * 2048, (size_t)2048 * 512);
    transpose_cast<<<dim3(512 / 32, 1024 / 32, NBLK), 256, 0, stream>>>(
        out_proj_w, Wot, 1024, 512, (size_t)1024 * 512, (size_t)512 * 1024);
    transpose_cast<<<dim3(2, 1024 / 32, NBLK), 256, 0, stream>>>(
        x_proj_w, Wxt, 1024, DBLW, (size_t)1024 * DBLW, (size_t)DBLW * 1024);

    for (int blk = 0; blk < NBLK; ++blk) {
        const unsigned short* Wit_b = Wit + (size_t)blk * 2048 * 512;
        const unsigned short* Wot_b = Wot + (size_t)blk * 512 * 1024;
        const unsigned short* Wxt_b = Wxt + (size_t)blk * DBLW * 1024;
        const float* cw  = conv_w    + (size_t)blk * DINNER * KCONV;
        const float* cb  = conv_b    + (size_t)blk * DINNER;
        const float* Wdt = dt_proj_w + (size_t)blk * DTRANK * DINNER;
        const float* bdt = dt_proj_b + (size_t)blk * DINNER;
        const float* Al  = A_log     + (size_t)blk * DINNER * DSTATE;
        const float* Dv  = Dp        + (size_t)blk * DINNER;

        // 1) xz_bf = bf16(xb @ Wit^T)   M=8192 N=2048 K=512
        gemm_bf16<<<dim3(2048 / 128, MROWS / 128), 256, 0, stream>>>(
            xb, DMODEL, Wit_b, DMODEL, DMODEL, 2 * DINNER, xz_bf, nullptr, 0);
        // 2) ub = bf16(silu(conv(xz_bf lo) + cb))
        conv_silu_kernel<<<(MROWS * DINNER) / 256, 256, 0, stream>>>(xz_bf, cw, cb, ub);
        // 3) dbl = ub @ Wxt^T (split-K atomics)
        zero_f32<<<(MROWS * DBLW / 4) / 256, 256, 0, stream>>>(dbl, MROWS * DBLW / 4);
        gemm_xproj<<<dim3(MROWS / 128, 4), 256, 0, stream>>>(ub, Wxt_b, dbl);
        // 4) delta = softplus(dbl[:, :32] @ Wdt + bdt)  fp32
        gemm_f32<<<dim3(DINNER / 64, MROWS / 64), 256, 0, stream>>>(
            dbl, DBLW, Wdt, DINNER, delta, DINNER, MROWS, DINNER, DTRANK, bdt, 1);
        // 5) chunked selective scan -> ybuf bf16
        {
            dim3 gridA(NC, DINNER / 256, BATCH_N);
            scan_chunk_kernel<<<gridA, 256, 0, stream>>>(delta, ub, dbl, Al, Pbuf, Sbuf);
            scan_combine_kernel<<<(BATCH_N * DINNER) / 256, 256, 0, stream>>>(Pbuf, Sbuf);
            scan_out_kernel<<<gridA, 256, 0, stream>>>(delta, ub, dbl, xz_bf, Al, Dv, Pbuf, ybuf);
        }
        // 6) x_buf += ybuf @ Wot^T (fp32); xb = bf16(x_buf)
        gemm_bf16<<<dim3(DMODEL / 128, MROWS / 128), 256, 0, stream>>>(
            ybuf, DINNER, Wot_b, DINNER, DINNER, DMODEL, xb, x_buf, 2);
    }

    // mean pool + classifier
    {
        dim3 grid1(POOL_SEGS, BATCH_N);
        pool1_kernel<<<grid1, DMODEL, 0, stream>>>(x_buf, part);
        pool2_kernel<<<BATCH_N, DMODEL, 0, stream>>>(part, pooled);
    }
    cls_kernel<<<1, 64, 0, stream>>>(pooled, cls_w, cls_b, out);
}

// Round 4
// 866.643 us; speedup vs baseline: 5.8864x; 1.0191x over previous
//
#include <hip/hip_runtime.h>
#include <cstddef>
#include <cstdint>

// Problem constants
#define L_SEQ   2048
#define BATCH_N 4
#define DMODEL  512
#define DINNER  1024
#define DSTATE  8
#define KCONV   4
#define DTRANK  32
#define NBLK    3
#define NCLS_N  10
#define MROWS   (BATCH_N * L_SEQ)   // 8192
#define DBLW    48                  // dt_rank + 2*d_state
#define NSPLIT  4                   // x_proj split-K planes

// Chunked-scan parameters
#define LC 64
#define NC (L_SEQ / LC)

typedef __attribute__((ext_vector_type(8))) short bf16x8;
typedef __attribute__((ext_vector_type(4))) float f32x4;

__device__ __forceinline__ float sigmoidf_(float x) { return 1.f / (1.f + expf(-x)); }
__device__ __forceinline__ float siluf_(float x)    { return x * sigmoidf_(x); }
__device__ __forceinline__ float softplusf_(float x){ return (x > 20.f) ? x : log1pf(expf(x)); }

__device__ __forceinline__ unsigned short f2bf(float f) {
    union { float f; uint32_t u; } v; v.f = f;
    const uint32_t u = v.u;
    return (unsigned short)((u + 0x7fffu + ((u >> 16) & 1u)) >> 16);  // RNE
}
__device__ __forceinline__ float bf2f(unsigned short h) {
    union { uint32_t u; float f; } v; v.u = ((uint32_t)h) << 16;
    return v.f;
}

// async global -> LDS, 16 bytes per lane; lds dest = wave-uniform base + lane*16
__device__ __forceinline__ void load_lds16(const void* g, void* l) {
    __builtin_amdgcn_global_load_lds(
        (const __attribute__((address_space(1))) unsigned int*)g,
        (__attribute__((address_space(3))) unsigned int*)l,
        16, 0, 0);
}

// ---------------------------------------------------------------------------
// bf16 MFMA GEMM: acc = A[M,K] @ Bt[N,K]^T, 128x128 tile, BK=64, 256 thr.
//   epi = 0: Obf = bf16(acc)
//   epi = 2: v = acc + Xres; Xres = v (fp32); Obf = bf16(v)
// ---------------------------------------------------------------------------
__global__ __launch_bounds__(256) void gemm_bf16(
    const unsigned short* __restrict__ A, int lda,
    const unsigned short* __restrict__ Bt, int ldb,
    int K, int ldc,
    unsigned short* __restrict__ Obf,
    float* __restrict__ Xres,
    int epi)
{
    __shared__ unsigned short sA[128 * 64];   // [row][k], row stride 64
    __shared__ unsigned short sB[128 * 64];   // [n][k]

    const int tid  = threadIdx.x;
    const int lane = tid & 63;
    const int wave = tid >> 6;
    const int m0 = blockIdx.y * 128;
    const int n0 = blockIdx.x * 128;
    const int wm = (wave >> 1) * 64;
    const int wn = (wave & 1) * 64;
    const int lm = lane & 15;
    const int lq = lane >> 4;

    const int srow = lane >> 3;
    const int scol = (lane & 7) * 8;

    f32x4 acc[4][4];
    #pragma unroll
    for (int i = 0; i < 4; ++i)
        #pragma unroll
        for (int j = 0; j < 4; ++j) acc[i][j] = (f32x4){0.f, 0.f, 0.f, 0.f};

    for (int k0 = 0; k0 < K; k0 += 64) {
        #pragma unroll
        for (int j = 0; j < 4; ++j) {
            const int c = j * 4 + wave;
            load_lds16(A  + (size_t)(m0 + c * 8 + srow) * lda + k0 + scol, &sA[c * 512]);
            load_lds16(Bt + (size_t)(n0 + c * 8 + srow) * ldb + k0 + scol, &sB[c * 512]);
        }
        __syncthreads();
        #pragma unroll
        for (int ks = 0; ks < 2; ++ks) {
            bf16x8 aF[4], bF[4];
            #pragma unroll
            for (int mt = 0; mt < 4; ++mt)
                aF[mt] = *(const bf16x8*)&sA[(wm + mt * 16 + lm) * 64 + ks * 32 + lq * 8];
            #pragma unroll
            for (int nt = 0; nt < 4; ++nt)
                bF[nt] = *(const bf16x8*)&sB[(wn + nt * 16 + lm) * 64 + ks * 32 + lq * 8];
            #pragma unroll
            for (int mt = 0; mt < 4; ++mt)
                #pragma unroll
                for (int nt = 0; nt < 4; ++nt)
                    acc[mt][nt] = __builtin_amdgcn_mfma_f32_16x16x32_bf16(
                        aF[mt], bF[nt], acc[mt][nt], 0, 0, 0);
        }
        __syncthreads();
    }

    #pragma unroll
    for (int mt = 0; mt < 4; ++mt) {
        #pragma unroll
        for (int nt = 0; nt < 4; ++nt) {
            #pragma unroll
            for (int r = 0; r < 4; ++r) {
                const int row = m0 + wm + mt * 16 + lq * 4 + r;
                const int col = n0 + wn + nt * 16 + lm;
                const size_t idx = (size_t)row * ldc + col;
                float v = acc[mt][nt][r];
                if (epi == 2) {
                    v += Xres[idx];
                    Xres[idx] = v;
                }
                Obf[idx] = f2bf(v);
            }
        }
    }
}

// ---------------------------------------------------------------------------
// x_proj: dbl4[s][M,48] = ub[M,1024] @ Wxt[48,1024]^T over k-slice s.
// Plain stores to per-split planes (consumers sum), no atomics.
// ---------------------------------------------------------------------------
__global__ __launch_bounds__(256) void gemm_xproj(
    const unsigned short* __restrict__ ub,
    const unsigned short* __restrict__ Wxt,
    float* __restrict__ dbl4)
{
    const int tid = threadIdx.x, lane = tid & 63, wave = tid >> 6;
    const int lm = lane & 15, lq = lane >> 4;
    const int rowA = blockIdx.x * 128 + wave * 32;
    const int split = blockIdx.y;
    const int k0 = split * (DINNER / NSPLIT);

    f32x4 acc[2][3];
    #pragma unroll
    for (int i = 0; i < 2; ++i)
        #pragma unroll
        for (int j = 0; j < 3; ++j) acc[i][j] = (f32x4){0.f, 0.f, 0.f, 0.f};

    for (int kk = 0; kk < DINNER / NSPLIT; kk += 32) {
        const int k = k0 + kk;
        bf16x8 aF[2], bF[3];
        #pragma unroll
        for (int mt = 0; mt < 2; ++mt)
            aF[mt] = *(const bf16x8*)&ub[(size_t)(rowA + mt * 16 + lm) * DINNER + k + lq * 8];
        #pragma unroll
        for (int nt = 0; nt < 3; ++nt)
            bF[nt] = *(const bf16x8*)&Wxt[(size_t)(nt * 16 + lm) * DINNER + k + lq * 8];
        #pragma unroll
        for (int mt = 0; mt < 2; ++mt)
            #pragma unroll
            for (int nt = 0; nt < 3; ++nt)
                acc[mt][nt] = __builtin_amdgcn_mfma_f32_16x16x32_bf16(
                    aF[mt], bF[nt], acc[mt][nt], 0, 0, 0);
    }
    #pragma unroll
    for (int mt = 0; mt < 2; ++mt)
        #pragma unroll
        for (int nt = 0; nt < 3; ++nt)
            #pragma unroll
            for (int r = 0; r < 4; ++r)
                dbl4[((size_t)split * MROWS + rowA + mt * 16 + lq * 4 + r) * DBLW
                     + nt * 16 + lm] = acc[mt][nt][r];
}

// ---------------------------------------------------------------------------
// dt_proj fused: delta_bf[M,1024] = bf16(softplus(sum_s dbl4[s][:, :32] @ Wdtt^T + bdt))
// One MFMA K-step (K=32), register streaming, no LDS.
// Grid: (DINNER/256, MROWS/64), 256 threads (4 waves, 16 rows each).
// ---------------------------------------------------------------------------
__global__ __launch_bounds__(256) void gemm_dt(
    const float* __restrict__ dbl4,          // (NSPLIT, M, 48)
    const unsigned short* __restrict__ Wdtt, // (1024, 32) bf16
    const float* __restrict__ bdt,           // (1024,)
    unsigned short* __restrict__ delta_bf)   // (M, 1024)
{
    const int lane = threadIdx.x & 63;
    const int wave = threadIdx.x >> 6;
    const int lm = lane & 15, lq = lane >> 4;
    const int m0 = blockIdx.y * 64 + wave * 16;

    // A-frag: row m0+lm, k = lq*8 + j, summed over splits
    float av[8];
    #pragma unroll
    for (int j = 0; j < 8; ++j) av[j] = 0.f;
    #pragma unroll
    for (int s = 0; s < NSPLIT; ++s) {
        const float* p = &dbl4[((size_t)s * MROWS + m0 + lm) * DBLW + lq * 8];
        float4 x0 = *(const float4*)p;
        float4 x1 = *(const float4*)(p + 4);
        av[0] += x0.x; av[1] += x0.y; av[2] += x0.z; av[3] += x0.w;
        av[4] += x1.x; av[5] += x1.y; av[6] += x1.z; av[7] += x1.w;
    }
    bf16x8 aF;
    #pragma unroll
    for (int j = 0; j < 8; ++j) aF[j] = (short)f2bf(av[j]);

    #pragma unroll
    for (int t = 0; t < 4; ++t) {
        const int n0 = blockIdx.x * 256 + t * 64;
        #pragma unroll
        for (int nt = 0; nt < 4; ++nt) {
            const int nb = n0 + nt * 16;
            bf16x8 bF = *(const bf16x8*)&Wdtt[(size_t)(nb + lm) * DTRANK + lq * 8];
            f32x4 acc = (f32x4){0.f, 0.f, 0.f, 0.f};
            acc = __builtin_amdgcn_mfma_f32_16x16x32_bf16(aF, bF, acc, 0, 0, 0);
            const int col = nb + lm;
            const float bias = bdt[col];
            #pragma unroll
            for (int r = 0; r < 4; ++r) {
                const int row = m0 + lq * 4 + r;
                delta_bf[(size_t)row * DINNER + col] = f2bf(softplusf_(acc[r] + bias));
            }
        }
    }
}

// ---------------------------------------------------------------------------
// Weight transpose + cast: out[n][k] bf16 = in[k][n] fp32
// ---------------------------------------------------------------------------
__global__ __launch_bounds__(256) void transpose_cast(
    const float* __restrict__ in, unsigned short* __restrict__ out,
    int Kdim, int Ndim, size_t in_stride, size_t out_stride)
{
    __shared__ float s[32][33];
    const float* ip = in + blockIdx.z * in_stride;
    unsigned short* op = out + blockIdx.z * out_stride;
    const int bx = blockIdx.x * 32;
    const int by = blockIdx.y * 32;
    const int t = threadIdx.x;
    const int r = t >> 3;
    const int c4 = (t & 7) * 4;

    const int row = by + r;
    if (bx + c4 + 3 < Ndim) {
        float4 v = *(const float4*)&ip[(size_t)row * Ndim + bx + c4];
        s[r][c4 + 0] = v.x; s[r][c4 + 1] = v.y; s[r][c4 + 2] = v.z; s[r][c4 + 3] = v.w;
    } else {
        for (int i = 0; i < 4; ++i) {
            const int col = bx + c4 + i;
            s[r][c4 + i] = (col < Ndim) ? ip[(size_t)row * Ndim + col] : 0.f;
        }
    }
    __syncthreads();
    if (bx + r < Ndim) {
        unsigned short w0 = f2bf(s[c4 + 0][r]), w1 = f2bf(s[c4 + 1][r]);
        unsigned short w2 = f2bf(s[c4 + 2][r]), w3 = f2bf(s[c4 + 3][r]);
        uint2 pk;
        pk.x = (uint32_t)w0 | ((uint32_t)w1 << 16);
        pk.y = (uint32_t)w2 | ((uint32_t)w3 << 16);
        *(uint2*)&op[(size_t)(bx + r) * Kdim + by + c4] = pk;
    }
}

__global__ void cast_bf16(const float* __restrict__ in, unsigned short* __restrict__ out, int n4) {
    const int i = blockIdx.x * 256 + threadIdx.x;
    if (i >= n4) return;
    float4 v = ((const float4*)in)[i];
    uint2 pk;
    pk.x = (uint32_t)f2bf(v.x) | ((uint32_t)f2bf(v.y) << 16);
    pk.y = (uint32_t)f2bf(v.z) | ((uint32_t)f2bf(v.w) << 16);
    ((uint2*)out)[i] = pk;
}

// ---------------------------------------------------------------------------
// Depthwise causal conv (K=4) + bias + SiLU; bf16 in (xz lo half), bf16 out.
// ---------------------------------------------------------------------------
__global__ __launch_bounds__(256) void conv_silu_kernel(
    const unsigned short* __restrict__ xz,
    const float* __restrict__ cw,
    const float* __restrict__ cb,
    unsigned short* __restrict__ ub)
{
    const int idx = blockIdx.x * 256 + threadIdx.x;
    const int d = idx & (DINNER - 1);
    const int m = idx >> 10;
    const int t = m & (L_SEQ - 1);

    float acc = cb[d];
    #pragma unroll
    for (int k = 0; k < KCONV; ++k) {
        const int tt = t + k - (KCONV - 1);
        if (tt >= 0)
            acc = fmaf(bf2f(xz[(size_t)(m - t + tt) * (2 * DINNER) + d]), cw[d * KCONV + k], acc);
    }
    ub[(size_t)m * DINNER + d] = f2bf(siluf_(acc));
}

// ---------------------------------------------------------------------------
// 3-phase chunked selective scan; delta bf16, u bf16, B/C summed from dbl4.
// ---------------------------------------------------------------------------
__global__ __launch_bounds__(256) void scan_chunk_kernel(
    const unsigned short* __restrict__ delta_bf,
    const unsigned short* __restrict__ ub,
    const float* __restrict__ dbl4,
    const float* __restrict__ A_log,
    float* __restrict__ Pbuf,
    float* __restrict__ Sbuf)
{
    const int c = blockIdx.x;
    const int d = blockIdx.y * 256 + threadIdx.x;
    const int b = blockIdx.z;
    const int tid = threadIdx.x;

    __shared__ float sB[LC][DSTATE];

    const size_t m0 = (size_t)b * L_SEQ + c * LC;
    #pragma unroll
    for (int i = tid; i < LC * DSTATE; i += 256) {
        const int r = i >> 3, n = i & 7;
        float v = 0.f;
        #pragma unroll
        for (int s = 0; s < NSPLIT; ++s)
            v += dbl4[((size_t)s * MROWS + m0 + r) * DBLW + DTRANK + n];
        sB[r][n] = v;
    }
    __syncthreads();

    float a[DSTATE], P[DSTATE], S[DSTATE];
    #pragma unroll
    for (int n = 0; n < DSTATE; ++n) {
        a[n] = -expf(A_log[d * DSTATE + n]);
        P[n] = 1.f;
        S[n] = 0.f;
    }

    for (int r = 0; r < LC; ++r) {
        const size_t m = m0 + r;
        const float dt = bf2f(delta_bf[m * DINNER + d]);
        const float ut = bf2f(ub[m * DINNER + d]);
        const float du = dt * ut;
        #pragma unroll
        for (int n = 0; n < DSTATE; ++n) {
            const float e = __expf(dt * a[n]);
            S[n] = fmaf(e, S[n], du * sB[r][n]);
            P[n] *= e;
        }
    }

    const size_t base = ((size_t)(b * NC + c) * DSTATE) * DINNER + d;
    #pragma unroll
    for (int n = 0; n < DSTATE; ++n) {
        Pbuf[base + (size_t)n * DINNER] = P[n];
        Sbuf[base + (size_t)n * DINNER] = S[n];
    }
}

__global__ __launch_bounds__(256) void scan_combine_kernel(
    float* __restrict__ Pbuf,
    const float* __restrict__ Sbuf)
{
    const int g = blockIdx.x * 256 + threadIdx.x;
    const int b = g >> 10;
    const int d = g & (DINNER - 1);

    float h[DSTATE];
    #pragma unroll
    for (int n = 0; n < DSTATE; ++n) h[n] = 0.f;

    for (int c = 0; c < NC; ++c) {
        const size_t base = ((size_t)(b * NC + c) * DSTATE) * DINNER + d;
        #pragma unroll
        for (int n = 0; n < DSTATE; ++n) {
            const size_t idx = base + (size_t)n * DINNER;
            const float p = Pbuf[idx];
            const float s = Sbuf[idx];
            Pbuf[idx] = h[n];
            h[n] = fmaf(p, h[n], s);
        }
    }
}

__global__ __launch_bounds__(256) void scan_out_kernel(
    const unsigned short* __restrict__ delta_bf,
    const unsigned short* __restrict__ ub,
    const float* __restrict__ dbl4,
    const unsigned short* __restrict__ xz,   // z at [., 1024+d]
    const float* __restrict__ A_log,
    const float* __restrict__ Dp,
    const float* __restrict__ Hin,
    unsigned short* __restrict__ ybuf)
{
    const int c = blockIdx.x;
    const int d = blockIdx.y * 256 + threadIdx.x;
    const int b = blockIdx.z;
    const int tid = threadIdx.x;

    __shared__ float sB[LC][DSTATE];
    __shared__ float sC[LC][DSTATE];

    const size_t m0 = (size_t)b * L_SEQ + c * LC;
    #pragma unroll
    for (int i = tid; i < LC * 2 * DSTATE; i += 256) {
        const int r = i >> 4, j = i & 15;
        float v = 0.f;
        #pragma unroll
        for (int s = 0; s < NSPLIT; ++s)
            v += dbl4[((size_t)s * MROWS + m0 + r) * DBLW + DTRANK + j];
        if (j < DSTATE) sB[r][j] = v;
        else            sC[r][j - DSTATE] = v;
    }
    __syncthreads();

    float a[DSTATE], h[DSTATE];
    const size_t base = ((size_t)(b * NC + c) * DSTATE) * DINNER + d;
    #pragma unroll
    for (int n = 0; n < DSTATE; ++n) {
        a[n] = -expf(A_log[d * DSTATE + n]);
        h[n] = Hin[base + (size_t)n * DINNER];
    }
    const float Dd = Dp[d];

    for (int r = 0; r < LC; ++r) {
        const size_t m = m0 + r;
        const float dt = bf2f(delta_bf[m * DINNER + d]);
        const float ut = bf2f(ub[m * DINNER + d]);
        const float du = dt * ut;
        float acc = 0.f;
        #pragma unroll
        for (int n = 0; n < DSTATE; ++n) {
            const float e = __expf(dt * a[n]);
            h[n] = fmaf(e, h[n], du * sB[r][n]);
            acc = fmaf(h[n], sC[r][n], acc);
        }
        const float z = bf2f(xz[m * (2 * DINNER) + DINNER + d]);
        ybuf[m * DINNER + d] = f2bf(fmaf(ut, Dd, acc) * siluf_(z));
    }
}

// ---------------------------------------------------------------------------
#define POOL_SEGS 16
__global__ __launch_bounds__(512) void pool1_kernel(
    const float* __restrict__ x, float* __restrict__ part)
{
    const int b = blockIdx.y;
    const int seg = blockIdx.x;
    const int dm = threadIdx.x;
    const int tpseg = L_SEQ / POOL_SEGS;
    float s = 0.f;
    for (int t = seg * tpseg; t < (seg + 1) * tpseg; ++t)
        s += x[((size_t)b * L_SEQ + t) * DMODEL + dm];
    part[((size_t)b * POOL_SEGS + seg) * DMODEL + dm] = s;
}

__global__ __launch_bounds__(512) void pool2_kernel(
    const float* __restrict__ part, float* __restrict__ pooled)
{
    const int b = blockIdx.x;
    const int dm = threadIdx.x;
    float s = 0.f;
    #pragma unroll
    for (int seg = 0; seg < POOL_SEGS; ++seg)
        s += part[((size_t)b * POOL_SEGS + seg) * DMODEL + dm];
    pooled[b * DMODEL + dm] = s * (1.f / (float)L_SEQ);
}

__global__ __launch_bounds__(64) void cls_kernel(
    const float* __restrict__ pooled,
    const float* __restrict__ w,
    const float* __restrict__ bias,
    float* __restrict__ out)
{
    const int tid = threadIdx.x;
    if (tid >= BATCH_N * NCLS_N) return;
    const int b = tid / NCLS_N;
    const int c = tid % NCLS_N;
    float s = bias[c];
    for (int k = 0; k < DMODEL; ++k)
        s = fmaf(pooled[b * DMODEL + k], w[k * NCLS_N + c], s);
    out[tid] = s;
}

// ---------------------------------------------------------------------------
extern "C" void kernel_launch(void* const* d_in, const int* in_sizes, int n_in,
                              void* d_out, int out_size, void* d_ws, size_t ws_size,
                              hipStream_t stream) {
    const float* x_in      = (const float*)d_in[0];
    const float* in_proj_w = (const float*)d_in[1];   // (3, 512, 2048)
    const float* conv_w    = (const float*)d_in[2];   // (3, 1024, 4)
    const float* conv_b    = (const float*)d_in[3];   // (3, 1024)
    const float* x_proj_w  = (const float*)d_in[4];   // (3, 1024, 48)
    const float* dt_proj_w = (const float*)d_in[5];   // (3, 32, 1024)
    const float* dt_proj_b = (const float*)d_in[6];   // (3, 1024)
    const float* A_log     = (const float*)d_in[7];   // (3, 1024, 8)
    const float* Dp        = (const float*)d_in[8];   // (3, 1024)
    const float* out_proj_w= (const float*)d_in[9];   // (3, 1024, 512)
    const float* cls_w     = (const float*)d_in[10];  // (512, 10)
    const float* cls_b     = (const float*)d_in[11];  // (10,)
    float* out = (float*)d_out;

    // Workspace layout (bytes, 256-aligned)
    char* w = (char*)d_ws;
    auto alloc = [&](size_t bytes) { char* p = w; w += (bytes + 255) & ~(size_t)255; return p; };
    float*          x_buf  = (float*)         alloc((size_t)MROWS * DMODEL * 4);       // 16 MB
    unsigned short* xz_bf  = (unsigned short*)alloc((size_t)MROWS * 2 * DINNER * 2);   // 32 MB
    unsigned short* ub     = (unsigned short*)alloc((size_t)MROWS * DINNER * 2);       // 16 MB
    unsigned short* delta  = (unsigned short*)alloc((size_t)MROWS * DINNER * 2);       // 16 MB
    float*          dbl4   = (float*)         alloc((size_t)NSPLIT * MROWS * DBLW * 4);// 6 MB
    float*          Pbuf   = (float*)         alloc((size_t)BATCH_N * NC * DSTATE * DINNER * 4);
    float*          Sbuf   = (float*)         alloc((size_t)BATCH_N * NC * DSTATE * DINNER * 4);
    unsigned short* xb     = (unsigned short*)alloc((size_t)MROWS * DMODEL * 2);       // 8 MB
    unsigned short* ybuf   = (unsigned short*)alloc((size_t)MROWS * DINNER * 2);       // 16 MB
    unsigned short* Wit    = (unsigned short*)alloc((size_t)NBLK * 2048 * 512 * 2);
    unsigned short* Wot    = (unsigned short*)alloc((size_t)NBLK * 512 * 1024 * 2);
    unsigned short* Wxt    = (unsigned short*)alloc((size_t)NBLK * DBLW * 1024 * 2);
    unsigned short* Wdtt   = (unsigned short*)alloc((size_t)NBLK * 1024 * DTRANK * 2);
    float*          part   = (float*)         alloc((size_t)BATCH_N * POOL_SEGS * DMODEL * 4);
    float*          pooled = (float*)         alloc((size_t)BATCH_N * DMODEL * 4);

    // Prep: residual fp32, bf16 cast of x, weight transposes+casts
    hipMemcpyAsync(x_buf, x_in, (size_t)MROWS * DMODEL * sizeof(float),
                   hipMemcpyDeviceToDevice, stream);
    cast_bf16<<<(MROWS * DMODEL / 4) / 256, 256, 0, stream>>>(x_in, xb, MROWS * DMODEL / 4);
    transpose_cast<<<dim3(2048 / 32, 512 / 32, NBLK), 256, 0, stream>>>(
        in_proj_w, Wit, 512, 2048, (size_t)512 * 2048, (size_t)2048 * 512);
    transpose_cast<<<dim3(512 / 32, 1024 / 32, NBLK), 256, 0, stream>>>(
        out_proj_w, Wot, 1024, 512, (size_t)1024 * 512, (size_t)512 * 1024);
    transpose_cast<<<dim3(2, 1024 / 32, NBLK), 256, 0, stream>>>(
        x_proj_w, Wxt, 1024, DBLW, (size_t)1024 * DBLW, (size_t)DBLW * 1024);
    transpose_cast<<<dim3(1024 / 32, 1, NBLK), 256, 0, stream>>>(
        dt_proj_w, Wdtt, DTRANK, 1024, (size_t)DTRANK * 1024, (size_t)1024 * DTRANK);

    for (int blk = 0; blk < NBLK; ++blk) {
        const unsigned short* Wit_b  = Wit  + (size_t)blk * 2048 * 512;
        const unsigned short* Wot_b  = Wot  + (size_t)blk * 512 * 1024;
        const unsigned short* Wxt_b  = Wxt  + (size_t)blk * DBLW * 1024;
        const unsigned short* Wdtt_b = Wdtt + (size_t)blk * 1024 * DTRANK;
        const float* cw  = conv_w    + (size_t)blk * DINNER * KCONV;
        const float* cb  = conv_b    + (size_t)blk * DINNER;
        const float* bdt = dt_proj_b + (size_t)blk * DINNER;
        const float* Al  = A_log     + (size_t)blk * DINNER * DSTATE;
        const float* Dv  = Dp        + (size_t)blk * DINNER;

        // 1) xz_bf = bf16(xb @ Wit^T)   M=8192 N=2048 K=512
        gemm_bf16<<<dim3(2048 / 128, MROWS / 128), 256, 0, stream>>>(
            xb, DMODEL, Wit_b, DMODEL, DMODEL, 2 * DINNER, xz_bf, nullptr, 0);
        // 2) ub = bf16(silu(conv(xz_bf lo) + cb))
        conv_silu_kernel<<<(MROWS * DINNER) / 256, 256, 0, stream>>>(xz_bf, cw, cb, ub);
        // 3) dbl4[s] = ub @ Wxt^T (k-slice planes, no atomics)
        gemm_xproj<<<dim3(MROWS / 128, NSPLIT), 256, 0, stream>>>(ub, Wxt_b, dbl4);
        // 4) delta = bf16(softplus(sum_s dbl4[s][:, :32] @ Wdtt^T + bdt))  MFMA
        gemm_dt<<<dim3(DINNER / 256, MROWS / 64), 256, 0, stream>>>(
            dbl4, Wdtt_b, bdt, delta);
        // 5) chunked selective scan -> ybuf bf16
        {
            dim3 gridA(NC, DINNER / 256, BATCH_N);
            scan_chunk_kernel<<<gridA, 256, 0, stream>>>(delta, ub, dbl4, Al, Pbuf, Sbuf);
            scan_combine_kernel<<<(BATCH_N * DINNER) / 256, 256, 0, stream>>>(Pbuf, Sbuf);
            scan_out_kernel<<<gridA, 256, 0, stream>>>(delta, ub, dbl4, xz_bf, Al, Dv, Pbuf, ybuf);
        }
        // 6) x_buf += ybuf @ Wot^T (fp32); xb = bf16(x_buf)
        gemm_bf16<<<dim3(DMODEL / 128, MROWS / 128), 256, 0, stream>>>(
            ybuf, DINNER, Wot_b, DINNER, DINNER, DMODEL, xb, x_buf, 2);
    }

    // mean pool + classifier
    {
        dim3 grid1(POOL_SEGS, BATCH_N);
        pool1_kernel<<<grid1, DMODEL, 0, stream>>>(x_buf, part);
        pool2_kernel<<<BATCH_N, DMODEL, 0, stream>>>(part, pooled);
    }
    cls_kernel<<<1, 64, 0, stream>>>(pooled, cls_w, cls_b, out);
}

// Round 5
// 823.647 us; speedup vs baseline: 6.1937x; 1.0522x over previous
//
#include <hip/hip_runtime.h>
#include <cstddef>
#include <cstdint>

// Problem constants
#define L_SEQ   2048
#define BATCH_N 4
#define DMODEL  512
#define DINNER  1024
#define DSTATE  8
#define KCONV   4
#define DTRANK  32
#define NBLK    3
#define NCLS_N  10
#define MROWS   (BATCH_N * L_SEQ)   // 8192
#define DBLW    48                  // dt_rank + 2*d_state
#define NSPLIT  4                   // x_proj split-K planes

// Chunked-scan parameters: LC2=32 rows/chunk, VD=4 channels/thread
#define LC2 32
#define NC2 (L_SEQ / LC2)   // 64
#define VD  4

typedef __attribute__((ext_vector_type(8))) short bf16x8;
typedef __attribute__((ext_vector_type(4))) short bf16x4;
typedef __attribute__((ext_vector_type(4))) float f32x4;

__device__ __forceinline__ float sigmoidf_(float x) { return 1.f / (1.f + expf(-x)); }
__device__ __forceinline__ float siluf_(float x)    { return x * sigmoidf_(x); }
__device__ __forceinline__ float softplusf_(float x){ return (x > 20.f) ? x : log1pf(expf(x)); }

__device__ __forceinline__ unsigned short f2bf(float f) {
    union { float f; uint32_t u; } v; v.f = f;
    const uint32_t u = v.u;
    return (unsigned short)((u + 0x7fffu + ((u >> 16) & 1u)) >> 16);  // RNE
}
__device__ __forceinline__ float bf2f(unsigned short h) {
    union { uint32_t u; float f; } v; v.u = ((uint32_t)h) << 16;
    return v.f;
}
__device__ __forceinline__ float bf2f_s(short h) { return bf2f((unsigned short)h); }

// async global -> LDS, 16 bytes per lane
__device__ __forceinline__ void load_lds16(const void* g, void* l) {
    __builtin_amdgcn_global_load_lds(
        (const __attribute__((address_space(1))) unsigned int*)g,
        (__attribute__((address_space(3))) unsigned int*)l,
        16, 0, 0);
}

// ---------------------------------------------------------------------------
// bf16 MFMA GEMM: acc = A[M,K] @ Bt[N,K]^T, 128x128 tile, BK=64, 256 thr.
//   epi = 0: Obf = bf16(acc)
//   epi = 2: v = acc + Xres; Xres = v (fp32); Obf = bf16(v)
// ---------------------------------------------------------------------------
__global__ __launch_bounds__(256) void gemm_bf16(
    const unsigned short* __restrict__ A, int lda,
    const unsigned short* __restrict__ Bt, int ldb,
    int K, int ldc,
    unsigned short* __restrict__ Obf,
    float* __restrict__ Xres,
    int epi)
{
    __shared__ unsigned short sA[128 * 64];
    __shared__ unsigned short sB[128 * 64];

    const int tid  = threadIdx.x;
    const int lane = tid & 63;
    const int wave = tid >> 6;
    const int m0 = blockIdx.y * 128;
    const int n0 = blockIdx.x * 128;
    const int wm = (wave >> 1) * 64;
    const int wn = (wave & 1) * 64;
    const int lm = lane & 15;
    const int lq = lane >> 4;

    const int srow = lane >> 3;
    const int scol = (lane & 7) * 8;

    f32x4 acc[4][4];
    #pragma unroll
    for (int i = 0; i < 4; ++i)
        #pragma unroll
        for (int j = 0; j < 4; ++j) acc[i][j] = (f32x4){0.f, 0.f, 0.f, 0.f};

    for (int k0 = 0; k0 < K; k0 += 64) {
        #pragma unroll
        for (int j = 0; j < 4; ++j) {
            const int c = j * 4 + wave;
            load_lds16(A  + (size_t)(m0 + c * 8 + srow) * lda + k0 + scol, &sA[c * 512]);
            load_lds16(Bt + (size_t)(n0 + c * 8 + srow) * ldb + k0 + scol, &sB[c * 512]);
        }
        __syncthreads();
        #pragma unroll
        for (int ks = 0; ks < 2; ++ks) {
            bf16x8 aF[4], bF[4];
            #pragma unroll
            for (int mt = 0; mt < 4; ++mt)
                aF[mt] = *(const bf16x8*)&sA[(wm + mt * 16 + lm) * 64 + ks * 32 + lq * 8];
            #pragma unroll
            for (int nt = 0; nt < 4; ++nt)
                bF[nt] = *(const bf16x8*)&sB[(wn + nt * 16 + lm) * 64 + ks * 32 + lq * 8];
            #pragma unroll
            for (int mt = 0; mt < 4; ++mt)
                #pragma unroll
                for (int nt = 0; nt < 4; ++nt)
                    acc[mt][nt] = __builtin_amdgcn_mfma_f32_16x16x32_bf16(
                        aF[mt], bF[nt], acc[mt][nt], 0, 0, 0);
        }
        __syncthreads();
    }

    #pragma unroll
    for (int mt = 0; mt < 4; ++mt) {
        #pragma unroll
        for (int nt = 0; nt < 4; ++nt) {
            #pragma unroll
            for (int r = 0; r < 4; ++r) {
                const int row = m0 + wm + mt * 16 + lq * 4 + r;
                const int col = n0 + wn + nt * 16 + lm;
                const size_t idx = (size_t)row * ldc + col;
                float v = acc[mt][nt][r];
                if (epi == 2) {
                    v += Xres[idx];
                    Xres[idx] = v;
                }
                Obf[idx] = f2bf(v);
            }
        }
    }
}

// ---------------------------------------------------------------------------
// x_proj: dbl4[s][M,48] = ub[M,1024] @ Wxt[48,1024]^T over k-slice s.
// ---------------------------------------------------------------------------
__global__ __launch_bounds__(256) void gemm_xproj(
    const unsigned short* __restrict__ ub,
    const unsigned short* __restrict__ Wxt,
    float* __restrict__ dbl4)
{
    const int tid = threadIdx.x, lane = tid & 63, wave = tid >> 6;
    const int lm = lane & 15, lq = lane >> 4;
    const int rowA = blockIdx.x * 128 + wave * 32;
    const int split = blockIdx.y;
    const int k0 = split * (DINNER / NSPLIT);

    f32x4 acc[2][3];
    #pragma unroll
    for (int i = 0; i < 2; ++i)
        #pragma unroll
        for (int j = 0; j < 3; ++j) acc[i][j] = (f32x4){0.f, 0.f, 0.f, 0.f};

    for (int kk = 0; kk < DINNER / NSPLIT; kk += 32) {
        const int k = k0 + kk;
        bf16x8 aF[2], bF[3];
        #pragma unroll
        for (int mt = 0; mt < 2; ++mt)
            aF[mt] = *(const bf16x8*)&ub[(size_t)(rowA + mt * 16 + lm) * DINNER + k + lq * 8];
        #pragma unroll
        for (int nt = 0; nt < 3; ++nt)
            bF[nt] = *(const bf16x8*)&Wxt[(size_t)(nt * 16 + lm) * DINNER + k + lq * 8];
        #pragma unroll
        for (int mt = 0; mt < 2; ++mt)
            #pragma unroll
            for (int nt = 0; nt < 3; ++nt)
                acc[mt][nt] = __builtin_amdgcn_mfma_f32_16x16x32_bf16(
                    aF[mt], bF[nt], acc[mt][nt], 0, 0, 0);
    }
    #pragma unroll
    for (int mt = 0; mt < 2; ++mt)
        #pragma unroll
        for (int nt = 0; nt < 3; ++nt)
            #pragma unroll
            for (int r = 0; r < 4; ++r)
                dbl4[((size_t)split * MROWS + rowA + mt * 16 + lq * 4 + r) * DBLW
                     + nt * 16 + lm] = acc[mt][nt][r];
}

// ---------------------------------------------------------------------------
// dt_proj fused: delta_bf = bf16(softplus(sum_s dbl4[s][:, :32] @ Wdtt^T + bdt))
// ---------------------------------------------------------------------------
__global__ __launch_bounds__(256) void gemm_dt(
    const float* __restrict__ dbl4,
    const unsigned short* __restrict__ Wdtt,
    const float* __restrict__ bdt,
    unsigned short* __restrict__ delta_bf)
{
    const int lane = threadIdx.x & 63;
    const int wave = threadIdx.x >> 6;
    const int lm = lane & 15, lq = lane >> 4;
    const int m0 = blockIdx.y * 64 + wave * 16;

    float av[8];
    #pragma unroll
    for (int j = 0; j < 8; ++j) av[j] = 0.f;
    #pragma unroll
    for (int s = 0; s < NSPLIT; ++s) {
        const float* p = &dbl4[((size_t)s * MROWS + m0 + lm) * DBLW + lq * 8];
        float4 x0 = *(const float4*)p;
        float4 x1 = *(const float4*)(p + 4);
        av[0] += x0.x; av[1] += x0.y; av[2] += x0.z; av[3] += x0.w;
        av[4] += x1.x; av[5] += x1.y; av[6] += x1.z; av[7] += x1.w;
    }
    bf16x8 aF;
    #pragma unroll
    for (int j = 0; j < 8; ++j) aF[j] = (short)f2bf(av[j]);

    #pragma unroll
    for (int t = 0; t < 4; ++t) {
        const int n0 = blockIdx.x * 256 + t * 64;
        #pragma unroll
        for (int nt = 0; nt < 4; ++nt) {
            const int nb = n0 + nt * 16;
            bf16x8 bF = *(const bf16x8*)&Wdtt[(size_t)(nb + lm) * DTRANK + lq * 8];
            f32x4 acc = (f32x4){0.f, 0.f, 0.f, 0.f};
            acc = __builtin_amdgcn_mfma_f32_16x16x32_bf16(aF, bF, acc, 0, 0, 0);
            const int col = nb + lm;
            const float bias = bdt[col];
            #pragma unroll
            for (int r = 0; r < 4; ++r) {
                const int row = m0 + lq * 4 + r;
                delta_bf[(size_t)row * DINNER + col] = f2bf(softplusf_(acc[r] + bias));
            }
        }
    }
}

// ---------------------------------------------------------------------------
// Weight transpose + cast: out[n][k] bf16 = in[k][n] fp32
// ---------------------------------------------------------------------------
__global__ __launch_bounds__(256) void transpose_cast(
    const float* __restrict__ in, unsigned short* __restrict__ out,
    int Kdim, int Ndim, size_t in_stride, size_t out_stride)
{
    __shared__ float s[32][33];
    const float* ip = in + blockIdx.z * in_stride;
    unsigned short* op = out + blockIdx.z * out_stride;
    const int bx = blockIdx.x * 32;
    const int by = blockIdx.y * 32;
    const int t = threadIdx.x;
    const int r = t >> 3;
    const int c4 = (t & 7) * 4;

    const int row = by + r;
    if (bx + c4 + 3 < Ndim) {
        float4 v = *(const float4*)&ip[(size_t)row * Ndim + bx + c4];
        s[r][c4 + 0] = v.x; s[r][c4 + 1] = v.y; s[r][c4 + 2] = v.z; s[r][c4 + 3] = v.w;
    } else {
        for (int i = 0; i < 4; ++i) {
            const int col = bx + c4 + i;
            s[r][c4 + i] = (col < Ndim) ? ip[(size_t)row * Ndim + col] : 0.f;
        }
    }
    __syncthreads();
    if (bx + r < Ndim) {
        unsigned short w0 = f2bf(s[c4 + 0][r]), w1 = f2bf(s[c4 + 1][r]);
        unsigned short w2 = f2bf(s[c4 + 2][r]), w3 = f2bf(s[c4 + 3][r]);
        uint2 pk;
        pk.x = (uint32_t)w0 | ((uint32_t)w1 << 16);
        pk.y = (uint32_t)w2 | ((uint32_t)w3 << 16);
        *(uint2*)&op[(size_t)(bx + r) * Kdim + by + c4] = pk;
    }
}

__global__ void cast_bf16(const float* __restrict__ in, unsigned short* __restrict__ out, int n4) {
    const int i = blockIdx.x * 256 + threadIdx.x;
    if (i >= n4) return;
    float4 v = ((const float4*)in)[i];
    uint2 pk;
    pk.x = (uint32_t)f2bf(v.x) | ((uint32_t)f2bf(v.y) << 16);
    pk.y = (uint32_t)f2bf(v.z) | ((uint32_t)f2bf(v.w) << 16);
    ((uint2*)out)[i] = pk;
}

// conv weight transpose: cwt[blk][k][d] = cw[blk][d][k]
__global__ void conv_w_transpose(const float* __restrict__ cw, float* __restrict__ cwt) {
    const int i = blockIdx.x * 256 + threadIdx.x;   // over NBLK*4096
    if (i >= NBLK * DINNER * KCONV) return;
    const int blk = i >> 12;
    const int rem = i & 4095;
    const int d = rem >> 2;
    const int k = rem & 3;
    cwt[blk * 4096 + k * DINNER + d] = cw[blk * 4096 + d * KCONV + k];
}

// ---------------------------------------------------------------------------
// Depthwise causal conv (K=4) + bias + SiLU; vectorized: 8 d per thread.
// ---------------------------------------------------------------------------
__global__ __launch_bounds__(256) void conv_silu_kernel(
    const unsigned short* __restrict__ xz,
    const float* __restrict__ cwt,   // (4, 1024) transposed
    const float* __restrict__ cb,
    unsigned short* __restrict__ ub)
{
    const int idx = blockIdx.x * 256 + threadIdx.x;   // over MROWS*128
    const int dv = idx & 127;
    const int m  = idx >> 7;
    const int t  = m & (L_SEQ - 1);
    const int d0 = dv * 8;

    float acc[8];
    {
        float4 c0 = *(const float4*)&cb[d0];
        float4 c1 = *(const float4*)&cb[d0 + 4];
        acc[0] = c0.x; acc[1] = c0.y; acc[2] = c0.z; acc[3] = c0.w;
        acc[4] = c1.x; acc[5] = c1.y; acc[6] = c1.z; acc[7] = c1.w;
    }
    #pragma unroll
    for (int k = 0; k < KCONV; ++k) {
        const int tt = t + k - (KCONV - 1);
        if (tt >= 0) {
            bf16x8 xv = *(const bf16x8*)&xz[(size_t)(m - t + tt) * (2 * DINNER) + d0];
            float4 w0 = *(const float4*)&cwt[k * DINNER + d0];
            float4 w1 = *(const float4*)&cwt[k * DINNER + d0 + 4];
            acc[0] = fmaf(bf2f_s(xv[0]), w0.x, acc[0]);
            acc[1] = fmaf(bf2f_s(xv[1]), w0.y, acc[1]);
            acc[2] = fmaf(bf2f_s(xv[2]), w0.z, acc[2]);
            acc[3] = fmaf(bf2f_s(xv[3]), w0.w, acc[3]);
            acc[4] = fmaf(bf2f_s(xv[4]), w1.x, acc[4]);
            acc[5] = fmaf(bf2f_s(xv[5]), w1.y, acc[5]);
            acc[6] = fmaf(bf2f_s(xv[6]), w1.z, acc[6]);
            acc[7] = fmaf(bf2f_s(xv[7]), w1.w, acc[7]);
        }
    }
    bf16x8 o;
    #pragma unroll
    for (int j = 0; j < 8; ++j) o[j] = (short)f2bf(siluf_(acc[j]));
    *(bf16x8*)&ub[(size_t)m * DINNER + d0] = o;
}

// ---------------------------------------------------------------------------
// 3-phase chunked selective scan; VD=4 channels/thread, LC2=32 rows/chunk.
// Layout of P/S/Hin: [b][c][n][d] -> ((b*NC2 + c)*DSTATE + n)*DINNER + d
// ---------------------------------------------------------------------------
__global__ __launch_bounds__(256) void scan_chunk_kernel(
    const unsigned short* __restrict__ delta_bf,
    const unsigned short* __restrict__ ub,
    const float* __restrict__ dbl4,
    const float* __restrict__ A_log,
    float* __restrict__ Pbuf,
    float* __restrict__ Sbuf)
{
    const int c = blockIdx.x;     // chunk
    const int b = blockIdx.y;
    const int tid = threadIdx.x;  // d-group (256 * VD = 1024 = DINNER)
    const int d0 = tid * VD;

    __shared__ float sB[LC2][DSTATE];

    const size_t m0 = (size_t)b * L_SEQ + c * LC2;
    if (tid < LC2 * DSTATE) {
        const int r = tid >> 3, n = tid & 7;
        float v = 0.f;
        #pragma unroll
        for (int s = 0; s < NSPLIT; ++s)
            v += dbl4[((size_t)s * MROWS + m0 + r) * DBLW + DTRANK + n];
        sB[r][n] = v;
    }
    __syncthreads();

    float a[DSTATE * VD], P[DSTATE * VD], S[DSTATE * VD];
    #pragma unroll
    for (int n = 0; n < DSTATE; ++n)
        #pragma unroll
        for (int v = 0; v < VD; ++v) {
            a[n * VD + v] = -expf(A_log[(d0 + v) * DSTATE + n]);
            P[n * VD + v] = 1.f;
            S[n * VD + v] = 0.f;
        }

    for (int r = 0; r < LC2; ++r) {
        const size_t m = m0 + r;
        bf16x4 dv = *(const bf16x4*)&delta_bf[m * DINNER + d0];
        bf16x4 uv = *(const bf16x4*)&ub[m * DINNER + d0];
        float dt[VD], du[VD];
        #pragma unroll
        for (int v = 0; v < VD; ++v) {
            dt[v] = bf2f_s(dv[v]);
            du[v] = dt[v] * bf2f_s(uv[v]);
        }
        #pragma unroll
        for (int n = 0; n < DSTATE; ++n) {
            const float bn = sB[r][n];
            #pragma unroll
            for (int v = 0; v < VD; ++v) {
                const float e = __expf(dt[v] * a[n * VD + v]);
                S[n * VD + v] = fmaf(e, S[n * VD + v], du[v] * bn);
                P[n * VD + v] *= e;
            }
        }
    }

    const size_t base = ((size_t)(b * NC2 + c) * DSTATE) * DINNER + d0;
    #pragma unroll
    for (int n = 0; n < DSTATE; ++n) {
        *(float4*)&Pbuf[base + (size_t)n * DINNER] = *(float4*)&P[n * VD];
        *(float4*)&Sbuf[base + (size_t)n * DINNER] = *(float4*)&S[n * VD];
    }
}

__global__ __launch_bounds__(256) void scan_combine_kernel(
    float* __restrict__ Pbuf,
    const float* __restrict__ Sbuf)
{
    const int g = blockIdx.x * 256 + threadIdx.x;   // over B*DINNER
    const int b = g >> 10;
    const int d = g & (DINNER - 1);

    float h[DSTATE];
    #pragma unroll
    for (int n = 0; n < DSTATE; ++n) h[n] = 0.f;

    for (int c = 0; c < NC2; ++c) {
        const size_t base = ((size_t)(b * NC2 + c) * DSTATE) * DINNER + d;
        #pragma unroll
        for (int n = 0; n < DSTATE; ++n) {
            const size_t idx = base + (size_t)n * DINNER;
            const float p = Pbuf[idx];
            const float s = Sbuf[idx];
            Pbuf[idx] = h[n];
            h[n] = fmaf(p, h[n], s);
        }
    }
}

__global__ __launch_bounds__(256) void scan_out_kernel(
    const unsigned short* __restrict__ delta_bf,
    const unsigned short* __restrict__ ub,
    const float* __restrict__ dbl4,
    const unsigned short* __restrict__ xz,   // z at [., 1024+d]
    const float* __restrict__ A_log,
    const float* __restrict__ Dp,
    const float* __restrict__ Hin,
    unsigned short* __restrict__ ybuf)
{
    const int c = blockIdx.x;
    const int b = blockIdx.y;
    const int tid = threadIdx.x;
    const int d0 = tid * VD;

    __shared__ float sB[LC2][DSTATE];
    __shared__ float sC[LC2][DSTATE];

    const size_t m0 = (size_t)b * L_SEQ + c * LC2;
    #pragma unroll
    for (int i = tid; i < LC2 * 2 * DSTATE; i += 256) {
        const int r = i >> 4, j = i & 15;
        float v = 0.f;
        #pragma unroll
        for (int s = 0; s < NSPLIT; ++s)
            v += dbl4[((size_t)s * MROWS + m0 + r) * DBLW + DTRANK + j];
        if (j < DSTATE) sB[r][j] = v;
        else            sC[r][j - DSTATE] = v;
    }
    __syncthreads();

    float a[DSTATE * VD], h[DSTATE * VD];
    const size_t base = ((size_t)(b * NC2 + c) * DSTATE) * DINNER + d0;
    #pragma unroll
    for (int n = 0; n < DSTATE; ++n) {
        float4 hv = *(const float4*)&Hin[base + (size_t)n * DINNER];
        h[n * VD + 0] = hv.x; h[n * VD + 1] = hv.y;
        h[n * VD + 2] = hv.z; h[n * VD + 3] = hv.w;
        #pragma unroll
        for (int v = 0; v < VD; ++v)
            a[n * VD + v] = -expf(A_log[(d0 + v) * DSTATE + n]);
    }
    float Dd[VD];
    {
        float4 dv4 = *(const float4*)&Dp[d0];
        Dd[0] = dv4.x; Dd[1] = dv4.y; Dd[2] = dv4.z; Dd[3] = dv4.w;
    }

    for (int r = 0; r < LC2; ++r) {
        const size_t m = m0 + r;
        bf16x4 dv = *(const bf16x4*)&delta_bf[m * DINNER + d0];
        bf16x4 uv = *(const bf16x4*)&ub[m * DINNER + d0];
        bf16x4 zv = *(const bf16x4*)&xz[m * (2 * DINNER) + DINNER + d0];
        float dt[VD], ut[VD], du[VD], acc[VD];
        #pragma unroll
        for (int v = 0; v < VD; ++v) {
            dt[v] = bf2f_s(dv[v]);
            ut[v] = bf2f_s(uv[v]);
            du[v] = dt[v] * ut[v];
            acc[v] = 0.f;
        }
        #pragma unroll
        for (int n = 0; n < DSTATE; ++n) {
            const float bn = sB[r][n];
            const float cn = sC[r][n];
            #pragma unroll
            for (int v = 0; v < VD; ++v) {
                const float e = __expf(dt[v] * a[n * VD + v]);
                h[n * VD + v] = fmaf(e, h[n * VD + v], du[v] * bn);
                acc[v] = fmaf(h[n * VD + v], cn, acc[v]);
            }
        }
        bf16x4 o;
        #pragma unroll
        for (int v = 0; v < VD; ++v)
            o[v] = (short)f2bf(fmaf(ut[v], Dd[v], acc[v]) * siluf_(bf2f_s(zv[v])));
        *(bf16x4*)&ybuf[m * DINNER + d0] = o;
    }
}

// ---------------------------------------------------------------------------
#define POOL_SEGS 16
__global__ __launch_bounds__(512) void pool1_kernel(
    const float* __restrict__ x, float* __restrict__ part)
{
    const int b = blockIdx.y;
    const int seg = blockIdx.x;
    const int dm = threadIdx.x;
    const int tpseg = L_SEQ / POOL_SEGS;
    float s = 0.f;
    for (int t = seg * tpseg; t < (seg + 1) * tpseg; ++t)
        s += x[((size_t)b * L_SEQ + t) * DMODEL + dm];
    part[((size_t)b * POOL_SEGS + seg) * DMODEL + dm] = s;
}

__global__ __launch_bounds__(512) void pool2_kernel(
    const float* __restrict__ part, float* __restrict__ pooled)
{
    const int b = blockIdx.x;
    const int dm = threadIdx.x;
    float s = 0.f;
    #pragma unroll
    for (int seg = 0; seg < POOL_SEGS; ++seg)
        s += part[((size_t)b * POOL_SEGS + seg) * DMODEL + dm];
    pooled[b * DMODEL + dm] = s * (1.f / (float)L_SEQ);
}

__global__ __launch_bounds__(64) void cls_kernel(
    const float* __restrict__ pooled,
    const float* __restrict__ w,
    const float* __restrict__ bias,
    float* __restrict__ out)
{
    const int tid = threadIdx.x;
    if (tid >= BATCH_N * NCLS_N) return;
    const int b = tid / NCLS_N;
    const int c = tid % NCLS_N;
    float s = bias[c];
    for (int k = 0; k < DMODEL; ++k)
        s = fmaf(pooled[b * DMODEL + k], w[k * NCLS_N + c], s);
    out[tid] = s;
}

// ---------------------------------------------------------------------------
extern "C" void kernel_launch(void* const* d_in, const int* in_sizes, int n_in,
                              void* d_out, int out_size, void* d_ws, size_t ws_size,
                              hipStream_t stream) {
    const float* x_in      = (const float*)d_in[0];
    const float* in_proj_w = (const float*)d_in[1];
    const float* conv_w    = (const float*)d_in[2];
    const float* conv_b    = (const float*)d_in[3];
    const float* x_proj_w  = (const float*)d_in[4];
    const float* dt_proj_w = (const float*)d_in[5];
    const float* dt_proj_b = (const float*)d_in[6];
    const float* A_log     = (const float*)d_in[7];
    const float* Dp        = (const float*)d_in[8];
    const float* out_proj_w= (const float*)d_in[9];
    const float* cls_w     = (const float*)d_in[10];
    const float* cls_b     = (const float*)d_in[11];
    float* out = (float*)d_out;

    // Workspace layout (bytes, 256-aligned)
    char* w = (char*)d_ws;
    auto alloc = [&](size_t bytes) { char* p = w; w += (bytes + 255) & ~(size_t)255; return p; };
    float*          x_buf  = (float*)         alloc((size_t)MROWS * DMODEL * 4);
    unsigned short* xz_bf  = (unsigned short*)alloc((size_t)MROWS * 2 * DINNER * 2);
    unsigned short* ub     = (unsigned short*)alloc((size_t)MROWS * DINNER * 2);
    unsigned short* delta  = (unsigned short*)alloc((size_t)MROWS * DINNER * 2);
    float*          dbl4   = (float*)         alloc((size_t)NSPLIT * MROWS * DBLW * 4);
    float*          Pbuf   = (float*)         alloc((size_t)BATCH_N * NC2 * DSTATE * DINNER * 4);
    float*          Sbuf   = (float*)         alloc((size_t)BATCH_N * NC2 * DSTATE * DINNER * 4);
    unsigned short* xb     = (unsigned short*)alloc((size_t)MROWS * DMODEL * 2);
    unsigned short* ybuf   = (unsigned short*)alloc((size_t)MROWS * DINNER * 2);
    unsigned short* Wit    = (unsigned short*)alloc((size_t)NBLK * 2048 * 512 * 2);
    unsigned short* Wot    = (unsigned short*)alloc((size_t)NBLK * 512 * 1024 * 2);
    unsigned short* Wxt    = (unsigned short*)alloc((size_t)NBLK * DBLW * 1024 * 2);
    unsigned short* Wdtt   = (unsigned short*)alloc((size_t)NBLK * 1024 * DTRANK * 2);
    float*          cwt    = (float*)         alloc((size_t)NBLK * KCONV * DINNER * 4);
    float*          part   = (float*)         alloc((size_t)BATCH_N * POOL_SEGS * DMODEL * 4);
    float*          pooled = (float*)         alloc((size_t)BATCH_N * DMODEL * 4);

    // Prep
    hipMemcpyAsync(x_buf, x_in, (size_t)MROWS * DMODEL * sizeof(float),
                   hipMemcpyDeviceToDevice, stream);
    cast_bf16<<<(MROWS * DMODEL / 4) / 256, 256, 0, stream>>>(x_in, xb, MROWS * DMODEL / 4);
    transpose_cast<<<dim3(2048 / 32, 512 / 32, NBLK), 256, 0, stream>>>(
        in_proj_w, Wit, 512, 2048, (size_t)512 * 2048, (size_t)2048 * 512);
    transpose_cast<<<dim3(512 / 32, 1024 / 32, NBLK), 256, 0, stream>>>(
        out_proj_w, Wot, 1024, 512, (size_t)1024 * 512, (size_t)512 * 1024);
    transpose_cast<<<dim3(2, 1024 / 32, NBLK), 256, 0, stream>>>(
        x_proj_w, Wxt, 1024, DBLW, (size_t)1024 * DBLW, (size_t)DBLW * 1024);
    transpose_cast<<<dim3(1024 / 32, 1, NBLK), 256, 0, stream>>>(
        dt_proj_w, Wdtt, DTRANK, 1024, (size_t)DTRANK * 1024, (size_t)1024 * DTRANK);
    conv_w_transpose<<<(NBLK * DINNER * KCONV + 255) / 256, 256, 0, stream>>>(conv_w, cwt);

    for (int blk = 0; blk < NBLK; ++blk) {
        const unsigned short* Wit_b  = Wit  + (size_t)blk * 2048 * 512;
        const unsigned short* Wot_b  = Wot  + (size_t)blk * 512 * 1024;
        const unsigned short* Wxt_b  = Wxt  + (size_t)blk * DBLW * 1024;
        const unsigned short* Wdtt_b = Wdtt + (size_t)blk * 1024 * DTRANK;
        const float* cwt_b = cwt + (size_t)blk * KCONV * DINNER;
        const float* cb  = conv_b    + (size_t)blk * DINNER;
        const float* bdt = dt_proj_b + (size_t)blk * DINNER;
        const float* Al  = A_log     + (size_t)blk * DINNER * DSTATE;
        const float* Dv  = Dp        + (size_t)blk * DINNER;

        // 1) xz_bf = bf16(xb @ Wit^T)
        gemm_bf16<<<dim3(2048 / 128, MROWS / 128), 256, 0, stream>>>(
            xb, DMODEL, Wit_b, DMODEL, DMODEL, 2 * DINNER, xz_bf, nullptr, 0);
        // 2) ub = bf16(silu(conv(xz_bf lo) + cb)) — vectorized x8
        conv_silu_kernel<<<(MROWS * 128) / 256, 256, 0, stream>>>(xz_bf, cwt_b, cb, ub);
        // 3) dbl4[s] = ub @ Wxt^T
        gemm_xproj<<<dim3(MROWS / 128, NSPLIT), 256, 0, stream>>>(ub, Wxt_b, dbl4);
        // 4) delta = bf16(softplus(dt @ Wdt + bdt))
        gemm_dt<<<dim3(DINNER / 256, MROWS / 64), 256, 0, stream>>>(
            dbl4, Wdtt_b, bdt, delta);
        // 5) chunked scan, VD=4
        {
            dim3 gridA(NC2, BATCH_N);
            scan_chunk_kernel<<<gridA, 256, 0, stream>>>(delta, ub, dbl4, Al, Pbuf, Sbuf);
            scan_combine_kernel<<<(BATCH_N * DINNER) / 256, 256, 0, stream>>>(Pbuf, Sbuf);
            scan_out_kernel<<<gridA, 256, 0, stream>>>(delta, ub, dbl4, xz_bf, Al, Dv, Pbuf, ybuf);
        }
        // 6) x_buf += ybuf @ Wot^T; xb = bf16(x_buf)
        gemm_bf16<<<dim3(DMODEL / 128, MROWS / 128), 256, 0, stream>>>(
            ybuf, DINNER, Wot_b, DINNER, DINNER, DMODEL, xb, x_buf, 2);
    }

    // mean pool + classifier
    {
        dim3 grid1(POOL_SEGS, BATCH_N);
        pool1_kernel<<<grid1, DMODEL, 0, stream>>>(x_buf, part);
        pool2_kernel<<<BATCH_N, DMODEL, 0, stream>>>(part, pooled);
    }
    cls_kernel<<<1, 64, 0, stream>>>(pooled, cls_w, cls_b, out);
}